// Round 4
// baseline (880.226 us; speedup 1.0000x reference)
//
#include <hip/hip_runtime.h>

#define NB 4      // batch
#define NC 32     // width (channels)
#define NH 256
#define NW 256
#define NM 16     // modes per dim
constexpr int NPIX = NH * NW;                 // 65536
constexpr int NP = NB * NC * NPIX;            // elements per per-o tensor (u32-packed)
constexpr int ZG = NB * NC * NM * NM * 2;     // floats per g for zred/zmix

typedef short bf16x8 __attribute__((ext_vector_type(8)));
typedef float f32x4  __attribute__((ext_vector_type(4)));
typedef unsigned short u16;
typedef unsigned int u32;

#define MFMA16(a, b, c) __builtin_amdgcn_mfma_f32_16x16x32_bf16(a, b, c, 0, 0, 0)

__device__ __forceinline__ u16 f2bf(float f) {
    unsigned u = __float_as_uint(f);
    u += 0x7FFFu + ((u >> 16) & 1u);
    return (u16)(u >> 16);
}
__device__ __forceinline__ float bf2f(u16 h) {
    return __uint_as_float(((unsigned)h) << 16);
}
// pack fp32 -> (hi bf16) | (lo bf16 << 16); consumers use exactly hi+lo
__device__ __forceinline__ u32 packsplit(float f) {
    const u16 hi = f2bf(f);
    const u16 lo = f2bf(f - bf2f(hi));
    return (u32)hi | ((u32)lo << 16);
}

// fast erf (A&S 7.1.26, |err| <= 1.5e-7) based exact-GELU
__device__ __forceinline__ float gelu_fast(float v) {
    const float ax = fabsf(v) * 0.70710678118654752f;
    const float t = __builtin_amdgcn_rcpf(1.0f + 0.3275911f * ax);
    const float y = t * (0.254829592f + t * (-0.284496736f + t * (1.421413741f +
                    t * (-1.453152027f + t * 1.061405429f))));
    const float e = __expf(-ax * ax);
    float er = 1.0f - y * e;
    er = copysignf(er, v);
    return 0.5f * v * (1.0f + er);
}

// ---------------------------------------------------------------------------
// Table prep: cw (inv B-operand, [n=256][k=32]) and eb (fwd DFT matrix,
// [row=32][w=256], scaled 1/16; applied twice -> 1/256 ortho norm).
// ---------------------------------------------------------------------------
__global__ __launch_bounds__(256) void tab_prep(
    u16* __restrict__ cwhi, u16* __restrict__ cwlo,
    u16* __restrict__ ebhi, u16* __restrict__ eblo)
{
    const int id = blockIdx.x * 256 + threadIdx.x;   // 0..16383
    if (id < 8192) {
        const int nn = id >> 5, k = id & 31;
        const int m = ((k & 15) * nn) & 255;
        float s, c;
        sincospif((float)m * (2.0f / 256.0f), &s, &c);
        const float v = (k < 16) ? c : s;
        const u16 hi = f2bf(v);
        cwhi[id] = hi;
        cwlo[id] = f2bf(v - bf2f(hi));
    } else {
        const int id2 = id - 8192;
        const int row = id2 >> 8, w = id2 & 255;
        const int m = ((row & 15) * w) & 255;
        float s, c;
        sincospif((float)m * (2.0f / 256.0f), &s, &c);
        const float v = 0.0625f * ((row < 16) ? c : s);
        const u16 hi = f2bf(v);
        ebhi[id2] = hi;
        eblo[id2] = f2bf(v - bf2f(hi));
    }
}

// ---------------------------------------------------------------------------
// Lift stage 1 (once per call): Y_lift[b][h][c*32+combo] (packed u32) from x.
// ---------------------------------------------------------------------------
__global__ __launch_bounds__(256) void s1_lift(
    const float* __restrict__ src,      // x[B,3,H,W]
    const float* __restrict__ lift_w,
    const float* __restrict__ lift_b,
    const u16* __restrict__ ebhi,
    const u16* __restrict__ eblo,
    u32* __restrict__ ypk)              // [b][h][1024]
{
    __shared__ u32 TrPk[64][33];        // [h-local][combo]

    const int tid = threadIdx.x;
    const int c  = blockIdx.x;
    const int b  = blockIdx.y;
    const int hq = blockIdx.z;
    const int wv = tid >> 6, lane = tid & 63;
    const int mrow = lane & 15, q = lane >> 4;
    const int hbase = hq * 64 + wv * 16;

    const float lw0 = lift_w[c * 3 + 0], lw1 = lift_w[c * 3 + 1], lw2 = lift_w[c * 3 + 2];
    const float lb = lift_b[c];
    const float* sb = src + (size_t)b * 3 * NPIX;

    f32x4 acc[2] = {};
    for (int ks = 0; ks < 8; ++ks) {
        bf16x8 bh[2], bl[2];
        #pragma unroll
        for (int nt = 0; nt < 2; ++nt) {
            const int off = (nt * 16 + mrow) * 256 + ks * 32 + q * 8;
            bh[nt] = *(const bf16x8*)(ebhi + off);
            bl[nt] = *(const bf16x8*)(eblo + off);
        }
        const float* xp = sb + (size_t)(hbase + mrow) * NW + ks * 32 + q * 8;
        const float4 p0a = *(const float4*)(xp);
        const float4 p0b = *(const float4*)(xp + 4);
        const float4 p1a = *(const float4*)(xp + NPIX);
        const float4 p1b = *(const float4*)(xp + NPIX + 4);
        const float4 p2a = *(const float4*)(xp + 2 * NPIX);
        const float4 p2b = *(const float4*)(xp + 2 * NPIX + 4);
        float v[8];
        v[0] = lw0 * p0a.x + lw1 * p1a.x + lw2 * p2a.x + lb;
        v[1] = lw0 * p0a.y + lw1 * p1a.y + lw2 * p2a.y + lb;
        v[2] = lw0 * p0a.z + lw1 * p1a.z + lw2 * p2a.z + lb;
        v[3] = lw0 * p0a.w + lw1 * p1a.w + lw2 * p2a.w + lb;
        v[4] = lw0 * p0b.x + lw1 * p1b.x + lw2 * p2b.x + lb;
        v[5] = lw0 * p0b.y + lw1 * p1b.y + lw2 * p2b.y + lb;
        v[6] = lw0 * p0b.z + lw1 * p1b.z + lw2 * p2b.z + lb;
        v[7] = lw0 * p0b.w + lw1 * p1b.w + lw2 * p2b.w + lb;
        bf16x8 xh, xl;
        #pragma unroll
        for (int j = 0; j < 8; ++j) {
            const u16 hi = f2bf(v[j]);
            xh[j] = (short)hi;
            xl[j] = (short)f2bf(v[j] - bf2f(hi));
        }
        #pragma unroll
        for (int nt = 0; nt < 2; ++nt) {
            acc[nt] = MFMA16(xh, bh[nt], acc[nt]);
            acc[nt] = MFMA16(xh, bl[nt], acc[nt]);
            acc[nt] = MFMA16(xl, bh[nt], acc[nt]);
        }
    }

    // C-layout: acc[nt][r] at (h-local = wv*16 + q*4 + r, combo = nt*16 + mrow)
    #pragma unroll
    for (int nt = 0; nt < 2; ++nt) {
        #pragma unroll
        for (int r = 0; r < 4; ++r)
            TrPk[wv * 16 + q * 4 + r][nt * 16 + mrow] = packsplit(acc[nt][r]);
    }
    __syncthreads();

    #pragma unroll
    for (int i = 0; i < 8; ++i) {
        const int idx = i * 256 + tid;
        const int hl = idx >> 5, combo = idx & 31;
        ypk[((size_t)b * 256 + hq * 64 + hl) * 1024 + c * 32 + combo] = TrPk[hl][combo];
    }
}

// ---------------------------------------------------------------------------
// s2: column-DFT P[kc][wc] = sum_h EB[kc][h] * Y[wc][h] + quadrant combine.
// ---------------------------------------------------------------------------
__global__ __launch_bounds__(256) void s2_kernel(
    const u32* __restrict__ ypk,
    const u16* __restrict__ ebhi,
    const u16* __restrict__ eblo,
    float* __restrict__ zred)
{
    __shared__ u32 Yl[256][33];         // [h][combo], pad 33
    __shared__ float P[32][33];

    const int tid = threadIdx.x;
    const int c  = blockIdx.x;
    const int gb = blockIdx.y;
    const int wv = tid >> 6, lane = tid & 63;
    const int mrow = lane & 15, q = lane >> 4;

    #pragma unroll
    for (int i = 0; i < 32; ++i) {
        const int idx = i * 256 + tid;
        const int h = idx >> 5, combo = idx & 31;
        Yl[h][combo] = ypk[((size_t)gb * 256 + h) * 1024 + c * 32 + combo];
    }
    __syncthreads();

    const int mt2 = wv >> 1, nt2 = wv & 1;
    const int wc = nt2 * 16 + mrow;
    f32x4 p = {};
    for (int ks = 0; ks < 8; ++ks) {
        const int aoff = (mt2 * 16 + mrow) * 256 + ks * 32 + q * 8;
        const bf16x8 ah = *(const bf16x8*)(ebhi + aoff);
        const bf16x8 al = *(const bf16x8*)(eblo + aoff);
        bf16x8 yh, yl;
        #pragma unroll
        for (int j = 0; j < 8; ++j) {
            const u32 v = Yl[ks * 32 + q * 8 + j][wc];
            yh[j] = (short)(v & 0xFFFFu);
            yl[j] = (short)(v >> 16);
        }
        p = MFMA16(ah, yh, p);
        p = MFMA16(ah, yl, p);
        p = MFMA16(al, yh, p);
    }
    #pragma unroll
    for (int r = 0; r < 4; ++r)
        P[mt2 * 16 + q * 4 + r][wc] = p[r];
    __syncthreads();

    // combine: Zr = Pcc - Pss, Zi = -(Pcs + Psc)
    const int k = tid >> 4, l = tid & 15;
    const float zr = P[k][l] - P[16 + k][16 + l];
    const float zi = -(P[k][16 + l] + P[16 + k][l]);
    const int idx = (gb * NC + c) * 256 + tid;
    zred[idx * 2 + 0] = zr;
    zred[idx * 2 + 1] = zi;
}

// ---------------------------------------------------------------------------
// Mode mix: grid (oc=32, mq=4, g=G); block 256.
// ---------------------------------------------------------------------------
__global__ __launch_bounds__(256) void mix_kernel(
    const float* __restrict__ zred,
    float* __restrict__ zmix,
    const float* __restrict__ wr,
    const float* __restrict__ wi,
    int o0, int n, int zgmul)
{
    __shared__ float ps[4][NB][64][2];
    const int tid = threadIdx.x;
    const int oc = blockIdx.x, mq = blockIdx.y, g = blockIdx.z;
    const int o = o0 + g, zg = zgmul * g;
    const int ichunk = tid >> 6, ml = tid & 63;
    const int mode = mq * 64 + ml;

    const float* wrb = wr + (size_t)(o * 4 + n) * NC * NC * 256;
    const float* wib = wi + (size_t)(o * 4 + n) * NC * NC * 256;

    float orr[NB] = {0.f, 0.f, 0.f, 0.f};
    float oii[NB] = {0.f, 0.f, 0.f, 0.f};

    #pragma unroll
    for (int ii = 0; ii < 8; ++ii) {
        const int i = ichunk * 8 + ii;
        const float wrv = wrb[(i * NC + oc) * 256 + mode];
        const float wiv = wib[(i * NC + oc) * 256 + mode];
        #pragma unroll
        for (int b = 0; b < NB; ++b) {
            const float2 z = *(const float2*)&zred[(((zg * NB + b) * NC + i) * 256 + mode) * 2];
            orr[b] += z.x * wrv - z.y * wiv;
            oii[b] += z.x * wiv + z.y * wrv;
        }
    }
    #pragma unroll
    for (int b = 0; b < NB; ++b) {
        ps[ichunk][b][ml][0] = orr[b];
        ps[ichunk][b][ml][1] = oii[b];
    }
    __syncthreads();

    const int b2 = tid >> 6, ml2 = tid & 63;
    float re = 0.f, im = 0.f;
    #pragma unroll
    for (int ic = 0; ic < 4; ++ic) {
        re += ps[ic][b2][ml2][0];
        im += ps[ic][b2][ml2][1];
    }
    const int oidx = ((g * NB + b2) * NC + oc) * 256 + mq * 64 + ml2;
    zmix[oidx * 2 + 0] = re;
    zmix[oidx * 2 + 1] = im;
}

// ---------------------------------------------------------------------------
// Inverse transform + bypass + GELU (+ projection if FINAL) + next layer's
// row-DFT Y if PRODY.
//
// Round-4 occupancy rework: the 32KB Ghi/Glo LDS staging is GONE. PRODY now
// reads its A-operand back from dstp (this block's own 32KB row, written in
// the main loop; __syncthreads() orders + drains the stores; rows are L1/L2
// resident). LDS = T/W (8KB, swizzled stride-32) + tw (2KB) + bbl/bweffs
// (512B) = 10,752 B -> wave-limited 8 blocks/CU (was LDS-limited 4).
// __launch_bounds__(256,8) caps VGPR at 64 (round 3 used 56) for 8 waves/EU.
// ---------------------------------------------------------------------------
template<bool LIFT, bool FINAL, bool PRODY>
__global__ __launch_bounds__(256, 8) void inv_kernel(
    const float* __restrict__ zmix,
    const void* __restrict__ srcv,      // LIFT ? float x : u32 xb
    const float* __restrict__ byp_w,
    const float* __restrict__ byp_b,
    const float* __restrict__ lift_w,
    const float* __restrict__ lift_b,
    const float* __restrict__ proj_w,
    const float* __restrict__ proj_b,
    const u16* __restrict__ cwhi,
    const u16* __restrict__ cwlo,
    const u16* __restrict__ ebhi,
    const u16* __restrict__ eblo,
    u32* __restrict__ ypk,              // [gb][h][1024] (PRODY)
    void* __restrict__ dstv,            // FINAL ? float out : u32 xb
    int o0, int n)
{
    // T/W: [32][32] u16, XOR-swizzled columns.
    __shared__ __align__(16) u16 Thi[NC * 32], Tlo[NC * 32];
    __shared__ __align__(16) u16 Whi[NC * 32], Wlo[NC * 32];
    __shared__ float2 tw[256];
    __shared__ float bbl[NC];
    __shared__ float bweffs[NC * 3];

    const int tid = threadIdx.x;
    const int h = blockIdx.x;
    const int gb = blockIdx.y;
    const int g = gb >> 2, b = gb & 3;
    const int o = o0 + g;
    const int lane = tid & 63, wv = tid >> 6;
    const int mrow = lane & 15, q = lane >> 4;

    {
        float s, cs;
        sincospif((float)tid * (2.0f / 256.0f), &s, &cs);
        tw[tid] = make_float2(cs, s);
    }

    const float* bwp = byp_w + (size_t)(o * 4 + n) * NC * NC;
    const float* bbp = byp_b + (o * 4 + n) * NC;

    if (LIFT) {
        if (tid < 96) {
            const int oc = tid / 3, j = tid % 3;
            float s = 0.f;
            for (int ic = 0; ic < NC; ++ic) s += bwp[oc * NC + ic] * lift_w[ic * 3 + j];
            bweffs[oc * 3 + j] = s;
        } else if (tid < 128) {
            const int oc = tid - 96;
            float s = bbp[oc];
            for (int ic = 0; ic < NC; ++ic) s += bwp[oc * NC + ic] * lift_b[ic];
            bbl[oc] = s;
        }
    } else {
        if (tid < NC) bbl[tid] = bbp[tid];
    }
    __syncthreads();

    for (int idx = tid; idx < NC * NC; idx += 256) {
        const int c = idx >> 5, ic = idx & 31;
        float v;
        if (LIFT) v = (ic < 3) ? bweffs[c * 3 + ic] : 0.f;
        else      v = bwp[idx];
        const u16 hi = f2bf(v);
        const int widx = c * 32 + (ic ^ ((c & 3) << 3));
        Whi[widx] = hi;
        Wlo[widx] = f2bf(v - bf2f(hi));
    }

    // phase A: T[c][l] from zmix; bias folded into T[c][0]
    #pragma unroll
    for (int rep = 0; rep < 2; ++rep) {
        const int it = rep * 256 + tid;
        const int c = it >> 4, l = it & 15;
        const float sl = (l == 0 ? 1.0f : 2.0f) / 256.0f;
        const float* zp = zmix + ((size_t)(gb * NC + c) * 256 + l) * 2;
        float tr = 0.f, ti = 0.f;
        int m = 0;
        #pragma unroll
        for (int k = 0; k < NM; ++k) {
            const float2 z = *(const float2*)(zp + k * 32);
            const float2 t = tw[m];
            tr += z.x * t.x - z.y * t.y;
            ti += z.x * t.y + z.y * t.x;
            m = (m + h) & 255;
        }
        tr *= sl; ti *= sl;
        if (l == 0) tr += bbl[c];
        const int sw = (c & 3) << 3;
        const u16 rh = f2bf(tr);
        Thi[c * 32 + (l ^ sw)] = rh;
        Tlo[c * 32 + (l ^ sw)] = f2bf(tr - bf2f(rh));
        const float nti_ = -ti;
        const u16 ih = f2bf(nti_);
        Thi[c * 32 + ((16 + l) ^ sw)] = ih;
        Tlo[c * 32 + ((16 + l) ^ sw)] = f2bf(nti_ - bf2f(ih));
    }
    __syncthreads();

    bf16x8 aThi[2], aTlo[2], aWhi[2], aWlo[2];
    #pragma unroll
    for (int mt = 0; mt < 2; ++mt) {
        const int ro = (mt * 16 + mrow) * 32 + 8 * (q ^ (mrow & 3));
        aThi[mt] = *(const bf16x8*)&Thi[ro];
        aTlo[mt] = *(const bf16x8*)&Tlo[ro];
        aWhi[mt] = *(const bf16x8*)&Whi[ro];
        aWlo[mt] = *(const bf16x8*)&Wlo[ro];
    }

    float pwv[8];
    float pb = 0.f;
    if (FINAL) {
        #pragma unroll
        for (int mt = 0; mt < 2; ++mt)
            #pragma unroll
            for (int i = 0; i < 4; ++i)
                pwv[mt * 4 + i] = proj_w[mt * 16 + q * 4 + i];
        pb = proj_b[0];
    }

    const float* xbf = LIFT ? (const float*)srcv + (size_t)b * 3 * NPIX + h * NW : nullptr;
    const u32*   xbp = LIFT ? nullptr : (const u32*)srcv + (size_t)gb * NC * NPIX + h * NW;
    u32*   dstp = (u32*)dstv;
    float* dstf = (float*)dstv;

    for (int nti = 0; nti < 4; ++nti) {
        const int nt = wv * 4 + nti;
        const int ncol = nt * 16 + mrow;

        const bf16x8 cwh = *(const bf16x8*)(cwhi + ncol * 32 + 8 * q);
        const bf16x8 cwl = *(const bf16x8*)(cwlo + ncol * 32 + 8 * q);

        bf16x8 xh, xl;
        #pragma unroll
        for (int j = 0; j < 8; ++j) {
            const int k = 8 * q + j;
            if (LIFT) {
                const float v = (k < 3) ? xbf[(size_t)k * NPIX + ncol] : 0.f;
                const u16 hi = f2bf(v);
                xh[j] = (short)hi;
                xl[j] = (short)f2bf(v - bf2f(hi));
            } else {
                const u32 p = xbp[(size_t)k * NPIX + ncol];
                xh[j] = (short)(p & 0xFFFFu);
                xl[j] = (short)(p >> 16);
            }
        }

        float fpart = 0.f;
        #pragma unroll
        for (int mt = 0; mt < 2; ++mt) {
            f32x4 acc = {0.f, 0.f, 0.f, 0.f};
            acc = MFMA16(aThi[mt], cwh, acc);
            acc = MFMA16(aThi[mt], cwl, acc);
            acc = MFMA16(aTlo[mt], cwh, acc);
            acc = MFMA16(aWhi[mt], xh, acc);
            acc = MFMA16(aWhi[mt], xl, acc);
            acc = MFMA16(aWlo[mt], xh, acc);
            if (FINAL) {
                #pragma unroll
                for (int i = 0; i < 4; ++i)
                    fpart += gelu_fast(acc[i]) * pwv[mt * 4 + i];
            } else {
                #pragma unroll
                for (int i = 0; i < 4; ++i) {
                    const int c = mt * 16 + q * 4 + i;
                    const float gl = gelu_fast(acc[i]);
                    dstp[((size_t)gb * NC + c) * NPIX + h * NW + ncol] = packsplit(gl);
                }
            }
        }
        if (FINAL) {
            fpart += __shfl_xor(fpart, 16);
            fpart += __shfl_xor(fpart, 32);
            if (q == 0) {
                dstf[(((size_t)b * 4 + o) * NH + h) * NW + nt * 16 + mrow] = fpart + pb;
            }
        }
    }

    // ---- appended (PRODY): next layer's row-DFT for this (h, gb) ----
    // A-operand read back from dstp (this block's own row, L1/L2-hot).
    if (PRODY) {
        __syncthreads();
        const int mt1 = wv >> 1, nt1 = wv & 1;   // 4 waves = 2x2 tiles
        const int r1 = mt1 * 16 + mrow;
        const u32* gsrc = dstp + ((size_t)gb * NC + r1) * NPIX + h * NW;
        f32x4 yacc = {};
        for (int ks = 0; ks < 8; ++ks) {
            const uint4 pa = *(const uint4*)(gsrc + ks * 32 + q * 8);
            const uint4 pc = *(const uint4*)(gsrc + ks * 32 + q * 8 + 4);
            const u32 pw[8] = {pa.x, pa.y, pa.z, pa.w, pc.x, pc.y, pc.z, pc.w};
            bf16x8 gh, gl;
            #pragma unroll
            for (int j = 0; j < 8; ++j) {
                gh[j] = (short)(pw[j] & 0xFFFFu);
                gl[j] = (short)(pw[j] >> 16);
            }
            const int bo = (nt1 * 16 + mrow) * 256 + ks * 32 + q * 8;
            const bf16x8 bh = *(const bf16x8*)(ebhi + bo);
            const bf16x8 bl = *(const bf16x8*)(eblo + bo);
            yacc = MFMA16(gh, bh, yacc);
            yacc = MFMA16(gh, bl, yacc);
            yacc = MFMA16(gl, bh, yacc);
        }
        u32* yout = ypk + ((size_t)gb * 256 + h) * 1024;
        #pragma unroll
        for (int r = 0; r < 4; ++r) {
            const int c = mt1 * 16 + q * 4 + r;
            const int combo = nt1 * 16 + mrow;
            yout[c * 32 + combo] = packsplit(yacc[r]);
        }
    }
}

// ---------------------------------------------------------------------------
extern "C" void kernel_launch(void* const* d_in, const int* in_sizes, int n_in,
                              void* d_out, int out_size, void* d_ws, size_t ws_size,
                              hipStream_t stream)
{
    const float* x      = (const float*)d_in[0];
    const float* lift_w = (const float*)d_in[1];
    const float* lift_b = (const float*)d_in[2];
    const float* wr     = (const float*)d_in[3];
    const float* wi     = (const float*)d_in[4];
    const float* byp_w  = (const float*)d_in[5];
    const float* byp_b  = (const float*)d_in[6];
    const float* proj_w = (const float*)d_in[7];
    const float* proj_b = (const float*)d_in[8];
    float* ws  = (float*)d_ws;

    const int G = 2;

    // ws: [cw/eb tables 16384 fl][zlift 65536][ylift 1M u32][y 2M u32]
    //     [zred G*ZG][zmix G*ZG][bufA][bufB]
    u16* cwhi = (u16*)ws;
    u16* cwlo = cwhi + 8192;
    u16* ebhi = cwlo + 8192;
    u16* eblo = ebhi + 8192;
    float* zlift = ws + 16384;
    u32* ylift = (u32*)(zlift + 65536);                      // 4*256*1024
    u32* y     = ylift + (size_t)4 * 256 * 1024;             // 8*256*1024
    float* zred = (float*)(y + (size_t)G * NB * 256 * 1024);
    float* zmix = zred + (size_t)G * ZG;
    u32* bufA = (u32*)(zmix + (size_t)G * ZG);
    u32* bufB = bufA + (size_t)G * NP;

    tab_prep<<<64, 256, 0, stream>>>(cwhi, cwlo, ebhi, eblo);

    // lift spectrum is o-independent: stage-1 + stage-2 once
    s1_lift<<<dim3(NC, NB, 4), 256, 0, stream>>>(x, lift_w, lift_b, ebhi, eblo, ylift);
    s2_kernel<<<dim3(NC, NB), 256, 0, stream>>>(ylift, ebhi, eblo, zlift);

    for (int o0 = 0; o0 < 4; o0 += G) {
        const u32* rd = nullptr;
        u32* wrbuf = bufA;
        for (int n = 0; n < 4; ++n) {
            const bool lift = (n == 0);
            const bool fin  = (n == 3);

            if (!lift)
                s2_kernel<<<dim3(NC, G * NB), 256, 0, stream>>>(y, ebhi, eblo, zred);

            mix_kernel<<<dim3(NC, 4, G), 256, 0, stream>>>(
                lift ? zlift : zred, zmix, wr, wi, o0, n, lift ? 0 : 1);

            dim3 igrid(NH, G * NB);
            if (fin) {
                inv_kernel<false, true, false><<<igrid, 256, 0, stream>>>(
                    zmix, rd, byp_w, byp_b, lift_w, lift_b, proj_w, proj_b,
                    cwhi, cwlo, ebhi, eblo, y, d_out, o0, n);
            } else if (lift) {
                inv_kernel<true, false, true><<<igrid, 256, 0, stream>>>(
                    zmix, x, byp_w, byp_b, lift_w, lift_b, proj_w, proj_b,
                    cwhi, cwlo, ebhi, eblo, y, wrbuf, o0, n);
            } else {
                inv_kernel<false, false, true><<<igrid, 256, 0, stream>>>(
                    zmix, rd, byp_w, byp_b, lift_w, lift_b, proj_w, proj_b,
                    cwhi, cwlo, ebhi, eblo, y, wrbuf, o0, n);
            }
            rd = wrbuf;
            wrbuf = (wrbuf == bufA) ? bufB : bufA;
        }
    }
}

// Round 5
// 498.816 us; speedup vs baseline: 1.7646x; 1.7646x over previous
//
#include <hip/hip_runtime.h>

#define NB 4      // batch
#define NC 32     // width (channels)
#define NH 256
#define NW 256
#define NM 16     // modes per dim
constexpr int NPIX = NH * NW;                 // 65536
constexpr int NP = NB * NC * NPIX;            // elements per per-o tensor (u32-packed)
constexpr int ZG = NB * NC * NM * NM * 2;     // floats per g for zred/zmix

typedef short bf16x8 __attribute__((ext_vector_type(8)));
typedef float f32x4  __attribute__((ext_vector_type(4)));
typedef unsigned short u16;
typedef unsigned int u32;

#define MFMA16(a, b, c) __builtin_amdgcn_mfma_f32_16x16x32_bf16(a, b, c, 0, 0, 0)

__device__ __forceinline__ u16 f2bf(float f) {
    unsigned u = __float_as_uint(f);
    u += 0x7FFFu + ((u >> 16) & 1u);
    return (u16)(u >> 16);
}
__device__ __forceinline__ float bf2f(u16 h) {
    return __uint_as_float(((unsigned)h) << 16);
}
// pack fp32 -> (hi bf16) | (lo bf16 << 16); consumers use exactly hi+lo
__device__ __forceinline__ u32 packsplit(float f) {
    const u16 hi = f2bf(f);
    const u16 lo = f2bf(f - bf2f(hi));
    return (u32)hi | ((u32)lo << 16);
}

// fast erf (A&S 7.1.26, |err| <= 1.5e-7) based exact-GELU
__device__ __forceinline__ float gelu_fast(float v) {
    const float ax = fabsf(v) * 0.70710678118654752f;
    const float t = __builtin_amdgcn_rcpf(1.0f + 0.3275911f * ax);
    const float y = t * (0.254829592f + t * (-0.284496736f + t * (1.421413741f +
                    t * (-1.453152027f + t * 1.061405429f))));
    const float e = __expf(-ax * ax);
    float er = 1.0f - y * e;
    er = copysignf(er, v);
    return 0.5f * v * (1.0f + er);
}

// ---------------------------------------------------------------------------
// Table prep: cw (inv B-operand, [n=256][k=32]) and eb (fwd DFT matrix,
// [row=32][w=256], scaled 1/16; applied twice -> 1/256 ortho norm).
// ---------------------------------------------------------------------------
__global__ __launch_bounds__(256) void tab_prep(
    u16* __restrict__ cwhi, u16* __restrict__ cwlo,
    u16* __restrict__ ebhi, u16* __restrict__ eblo)
{
    const int id = blockIdx.x * 256 + threadIdx.x;   // 0..16383
    if (id < 8192) {
        const int nn = id >> 5, k = id & 31;
        const int m = ((k & 15) * nn) & 255;
        float s, c;
        sincospif((float)m * (2.0f / 256.0f), &s, &c);
        const float v = (k < 16) ? c : s;
        const u16 hi = f2bf(v);
        cwhi[id] = hi;
        cwlo[id] = f2bf(v - bf2f(hi));
    } else {
        const int id2 = id - 8192;
        const int row = id2 >> 8, w = id2 & 255;
        const int m = ((row & 15) * w) & 255;
        float s, c;
        sincospif((float)m * (2.0f / 256.0f), &s, &c);
        const float v = 0.0625f * ((row < 16) ? c : s);
        const u16 hi = f2bf(v);
        ebhi[id2] = hi;
        eblo[id2] = f2bf(v - bf2f(hi));
    }
}

// ---------------------------------------------------------------------------
// Lift stage 1 (once per call): Y_lift[b][h][c*32+combo] (packed u32) from x.
// ---------------------------------------------------------------------------
__global__ __launch_bounds__(256) void s1_lift(
    const float* __restrict__ src,      // x[B,3,H,W]
    const float* __restrict__ lift_w,
    const float* __restrict__ lift_b,
    const u16* __restrict__ ebhi,
    const u16* __restrict__ eblo,
    u32* __restrict__ ypk)              // [b][h][1024]
{
    __shared__ u32 TrPk[64][33];        // [h-local][combo]

    const int tid = threadIdx.x;
    const int c  = blockIdx.x;
    const int b  = blockIdx.y;
    const int hq = blockIdx.z;
    const int wv = tid >> 6, lane = tid & 63;
    const int mrow = lane & 15, q = lane >> 4;
    const int hbase = hq * 64 + wv * 16;

    const float lw0 = lift_w[c * 3 + 0], lw1 = lift_w[c * 3 + 1], lw2 = lift_w[c * 3 + 2];
    const float lb = lift_b[c];
    const float* sb = src + (size_t)b * 3 * NPIX;

    f32x4 acc[2] = {};
    for (int ks = 0; ks < 8; ++ks) {
        bf16x8 bh[2], bl[2];
        #pragma unroll
        for (int nt = 0; nt < 2; ++nt) {
            const int off = (nt * 16 + mrow) * 256 + ks * 32 + q * 8;
            bh[nt] = *(const bf16x8*)(ebhi + off);
            bl[nt] = *(const bf16x8*)(eblo + off);
        }
        const float* xp = sb + (size_t)(hbase + mrow) * NW + ks * 32 + q * 8;
        const float4 p0a = *(const float4*)(xp);
        const float4 p0b = *(const float4*)(xp + 4);
        const float4 p1a = *(const float4*)(xp + NPIX);
        const float4 p1b = *(const float4*)(xp + NPIX + 4);
        const float4 p2a = *(const float4*)(xp + 2 * NPIX);
        const float4 p2b = *(const float4*)(xp + 2 * NPIX + 4);
        float v[8];
        v[0] = lw0 * p0a.x + lw1 * p1a.x + lw2 * p2a.x + lb;
        v[1] = lw0 * p0a.y + lw1 * p1a.y + lw2 * p2a.y + lb;
        v[2] = lw0 * p0a.z + lw1 * p1a.z + lw2 * p2a.z + lb;
        v[3] = lw0 * p0a.w + lw1 * p1a.w + lw2 * p2a.w + lb;
        v[4] = lw0 * p0b.x + lw1 * p1b.x + lw2 * p2b.x + lb;
        v[5] = lw0 * p0b.y + lw1 * p1b.y + lw2 * p2b.y + lb;
        v[6] = lw0 * p0b.z + lw1 * p1b.z + lw2 * p2b.z + lb;
        v[7] = lw0 * p0b.w + lw1 * p1b.w + lw2 * p2b.w + lb;
        bf16x8 xh, xl;
        #pragma unroll
        for (int j = 0; j < 8; ++j) {
            const u16 hi = f2bf(v[j]);
            xh[j] = (short)hi;
            xl[j] = (short)f2bf(v[j] - bf2f(hi));
        }
        #pragma unroll
        for (int nt = 0; nt < 2; ++nt) {
            acc[nt] = MFMA16(xh, bh[nt], acc[nt]);
            acc[nt] = MFMA16(xh, bl[nt], acc[nt]);
            acc[nt] = MFMA16(xl, bh[nt], acc[nt]);
        }
    }

    // C-layout: acc[nt][r] at (h-local = wv*16 + q*4 + r, combo = nt*16 + mrow)
    #pragma unroll
    for (int nt = 0; nt < 2; ++nt) {
        #pragma unroll
        for (int r = 0; r < 4; ++r)
            TrPk[wv * 16 + q * 4 + r][nt * 16 + mrow] = packsplit(acc[nt][r]);
    }
    __syncthreads();

    #pragma unroll
    for (int i = 0; i < 8; ++i) {
        const int idx = i * 256 + tid;
        const int hl = idx >> 5, combo = idx & 31;
        ypk[((size_t)b * 256 + hq * 64 + hl) * 1024 + c * 32 + combo] = TrPk[hl][combo];
    }
}

// ---------------------------------------------------------------------------
// s2: column-DFT P[kc][wc] = sum_h EB[kc][h] * Y[wc][h] + quadrant combine.
// ---------------------------------------------------------------------------
__global__ __launch_bounds__(256) void s2_kernel(
    const u32* __restrict__ ypk,
    const u16* __restrict__ ebhi,
    const u16* __restrict__ eblo,
    float* __restrict__ zred)
{
    __shared__ u32 Yl[256][33];         // [h][combo], pad 33
    __shared__ float P[32][33];

    const int tid = threadIdx.x;
    const int c  = blockIdx.x;
    const int gb = blockIdx.y;
    const int wv = tid >> 6, lane = tid & 63;
    const int mrow = lane & 15, q = lane >> 4;

    #pragma unroll
    for (int i = 0; i < 32; ++i) {
        const int idx = i * 256 + tid;
        const int h = idx >> 5, combo = idx & 31;
        Yl[h][combo] = ypk[((size_t)gb * 256 + h) * 1024 + c * 32 + combo];
    }
    __syncthreads();

    const int mt2 = wv >> 1, nt2 = wv & 1;
    const int wc = nt2 * 16 + mrow;
    f32x4 p = {};
    for (int ks = 0; ks < 8; ++ks) {
        const int aoff = (mt2 * 16 + mrow) * 256 + ks * 32 + q * 8;
        const bf16x8 ah = *(const bf16x8*)(ebhi + aoff);
        const bf16x8 al = *(const bf16x8*)(eblo + aoff);
        bf16x8 yh, yl;
        #pragma unroll
        for (int j = 0; j < 8; ++j) {
            const u32 v = Yl[ks * 32 + q * 8 + j][wc];
            yh[j] = (short)(v & 0xFFFFu);
            yl[j] = (short)(v >> 16);
        }
        p = MFMA16(ah, yh, p);
        p = MFMA16(ah, yl, p);
        p = MFMA16(al, yh, p);
    }
    #pragma unroll
    for (int r = 0; r < 4; ++r)
        P[mt2 * 16 + q * 4 + r][wc] = p[r];
    __syncthreads();

    // combine: Zr = Pcc - Pss, Zi = -(Pcs + Psc)
    const int k = tid >> 4, l = tid & 15;
    const float zr = P[k][l] - P[16 + k][16 + l];
    const float zi = -(P[k][16 + l] + P[16 + k][l]);
    const int idx = (gb * NC + c) * 256 + tid;
    zred[idx * 2 + 0] = zr;
    zred[idx * 2 + 1] = zi;
}

// ---------------------------------------------------------------------------
// Mode mix: grid (oc=32, mq=4, g=G); block 256.
// ---------------------------------------------------------------------------
__global__ __launch_bounds__(256) void mix_kernel(
    const float* __restrict__ zred,
    float* __restrict__ zmix,
    const float* __restrict__ wr,
    const float* __restrict__ wi,
    int o0, int n, int zgmul)
{
    __shared__ float ps[4][NB][64][2];
    const int tid = threadIdx.x;
    const int oc = blockIdx.x, mq = blockIdx.y, g = blockIdx.z;
    const int o = o0 + g, zg = zgmul * g;
    const int ichunk = tid >> 6, ml = tid & 63;
    const int mode = mq * 64 + ml;

    const float* wrb = wr + (size_t)(o * 4 + n) * NC * NC * 256;
    const float* wib = wi + (size_t)(o * 4 + n) * NC * NC * 256;

    float orr[NB] = {0.f, 0.f, 0.f, 0.f};
    float oii[NB] = {0.f, 0.f, 0.f, 0.f};

    #pragma unroll
    for (int ii = 0; ii < 8; ++ii) {
        const int i = ichunk * 8 + ii;
        const float wrv = wrb[(i * NC + oc) * 256 + mode];
        const float wiv = wib[(i * NC + oc) * 256 + mode];
        #pragma unroll
        for (int b = 0; b < NB; ++b) {
            const float2 z = *(const float2*)&zred[(((zg * NB + b) * NC + i) * 256 + mode) * 2];
            orr[b] += z.x * wrv - z.y * wiv;
            oii[b] += z.x * wiv + z.y * wrv;
        }
    }
    #pragma unroll
    for (int b = 0; b < NB; ++b) {
        ps[ichunk][b][ml][0] = orr[b];
        ps[ichunk][b][ml][1] = oii[b];
    }
    __syncthreads();

    const int b2 = tid >> 6, ml2 = tid & 63;
    float re = 0.f, im = 0.f;
    #pragma unroll
    for (int ic = 0; ic < 4; ++ic) {
        re += ps[ic][b2][ml2][0];
        im += ps[ic][b2][ml2][1];
    }
    const int oidx = ((g * NB + b2) * NC + oc) * 256 + mq * 64 + ml2;
    zmix[oidx * 2 + 0] = re;
    zmix[oidx * 2 + 1] = im;
}

// ---------------------------------------------------------------------------
// Inverse transform + bypass + GELU (+ projection if FINAL) + next layer's
// row-DFT Y if PRODY.
//
// Round-5: EXACT round-0 structure (50688B LDS, 3 blocks/CU, the only
// measured-good config at 51.5us; occupancy experiments r1-r4 all regressed)
// with three ILP-only edits, none extending a live range across a barrier:
//  (1) depth-1 prefetch of the next nti's 8 bypass words (live range = one
//      unrolled iteration; r1/r2's kernel-length prefetch spilled).
//  (2) main accumulator split accT/accW: T-chain has no load dependency and
//      issues immediately; W-chain starts when loads land. 6-chain -> 2x3.
//  (3) PRODY 24-long serial yacc chain -> 3 independent 8-chains (one per
//      product term), summed at the end.
// ---------------------------------------------------------------------------
template<bool LIFT, bool FINAL, bool PRODY>
__global__ __launch_bounds__(256) void inv_kernel(
    const float* __restrict__ zmix,
    const void* __restrict__ srcv,      // LIFT ? float x : u32 xb
    const float* __restrict__ byp_w,
    const float* __restrict__ byp_b,
    const float* __restrict__ lift_w,
    const float* __restrict__ lift_b,
    const float* __restrict__ proj_w,
    const float* __restrict__ proj_b,
    const u16* __restrict__ cwhi,
    const u16* __restrict__ cwlo,
    const u16* __restrict__ ebhi,
    const u16* __restrict__ eblo,
    u32* __restrict__ ypk,              // [gb][h][1024] (PRODY)
    void* __restrict__ dstv,            // FINAL ? float out : u32 xb
    int o0, int n)
{
    __shared__ float2 tw[256];
    __shared__ u16 Thi[NC * 40], Tlo[NC * 40];
    __shared__ u16 Whi[NC * 40], Wlo[NC * 40];
    __shared__ float bbl[NC];
    __shared__ float bweffs[NC * 3];
    __shared__ u16 Ghi[PRODY ? 32 * 264 : 1];
    __shared__ u16 Glo[PRODY ? 32 * 264 : 1];
    __shared__ u32 Ypks[PRODY ? 1024 : 1];

    const int tid = threadIdx.x;
    const int h = blockIdx.x;
    const int gb = blockIdx.y;
    const int g = gb >> 2, b = gb & 3;
    const int o = o0 + g;

    {
        float s, cs;
        sincospif((float)tid * (2.0f / 256.0f), &s, &cs);
        tw[tid] = make_float2(cs, s);
    }

    const float* bwp = byp_w + (size_t)(o * 4 + n) * NC * NC;
    const float* bbp = byp_b + (o * 4 + n) * NC;

    if (LIFT) {
        if (tid < 96) {
            const int oc = tid / 3, j = tid % 3;
            float s = 0.f;
            for (int ic = 0; ic < NC; ++ic) s += bwp[oc * NC + ic] * lift_w[ic * 3 + j];
            bweffs[oc * 3 + j] = s;
        } else if (tid < 128) {
            const int oc = tid - 96;
            float s = bbp[oc];
            for (int ic = 0; ic < NC; ++ic) s += bwp[oc * NC + ic] * lift_b[ic];
            bbl[oc] = s;
        }
    } else {
        if (tid < NC) bbl[tid] = bbp[tid];
    }
    __syncthreads();

    for (int idx = tid; idx < NC * NC; idx += 256) {
        const int c = idx >> 5, ic = idx & 31;
        float v;
        if (LIFT) v = (ic < 3) ? bweffs[c * 3 + ic] : 0.f;
        else      v = bwp[idx];
        const u16 hi = f2bf(v);
        Whi[c * 40 + ic] = hi;
        Wlo[c * 40 + ic] = f2bf(v - bf2f(hi));
    }

    // phase A: T[c][l] from zmix; bias folded into T[c][0]
    #pragma unroll
    for (int rep = 0; rep < 2; ++rep) {
        const int it = rep * 256 + tid;
        const int c = it >> 4, l = it & 15;
        const float sl = (l == 0 ? 1.0f : 2.0f) / 256.0f;
        const float* zp = zmix + ((size_t)(gb * NC + c) * 256 + l) * 2;
        float tr = 0.f, ti = 0.f;
        int m = 0;
        #pragma unroll
        for (int k = 0; k < NM; ++k) {
            const float2 z = *(const float2*)(zp + k * 32);
            const float2 t = tw[m];
            tr += z.x * t.x - z.y * t.y;
            ti += z.x * t.y + z.y * t.x;
            m = (m + h) & 255;
        }
        tr *= sl; ti *= sl;
        if (l == 0) tr += bbl[c];
        const u16 rh = f2bf(tr);
        Thi[c * 40 + l] = rh;
        Tlo[c * 40 + l] = f2bf(tr - bf2f(rh));
        const float nti_ = -ti;
        const u16 ih = f2bf(nti_);
        Thi[c * 40 + 16 + l] = ih;
        Tlo[c * 40 + 16 + l] = f2bf(nti_ - bf2f(ih));
    }
    __syncthreads();

    const int lane = tid & 63, wv = tid >> 6;
    const int mrow = lane & 15, q = lane >> 4;

    bf16x8 aThi[2], aTlo[2], aWhi[2], aWlo[2];
    #pragma unroll
    for (int mt = 0; mt < 2; ++mt) {
        const int ro = (mt * 16 + mrow) * 40 + 8 * q;
        aThi[mt] = *(const bf16x8*)&Thi[ro];
        aTlo[mt] = *(const bf16x8*)&Tlo[ro];
        aWhi[mt] = *(const bf16x8*)&Whi[ro];
        aWlo[mt] = *(const bf16x8*)&Wlo[ro];
    }

    float pwv[8];
    float pb = 0.f;
    if (FINAL) {
        #pragma unroll
        for (int mt = 0; mt < 2; ++mt)
            #pragma unroll
            for (int i = 0; i < 4; ++i)
                pwv[mt * 4 + i] = proj_w[mt * 16 + q * 4 + i];
        pb = proj_b[0];
    }

    const float* xbf = LIFT ? (const float*)srcv + (size_t)b * 3 * NPIX + h * NW : nullptr;
    const u32*   xbp = LIFT ? nullptr : (const u32*)srcv + (size_t)gb * NC * NPIX + h * NW;
    u32*   dstp = (u32*)dstv;
    float* dstf = (float*)dstv;

    // depth-1 prefetch of the bypass row (non-LIFT path only)
    u32 cur[8];
    if (!LIFT) {
        const int ncol0 = (wv * 4 + 0) * 16 + mrow;
        #pragma unroll
        for (int j = 0; j < 8; ++j)
            cur[j] = xbp[(size_t)(8 * q + j) * NPIX + ncol0];
    }

    #pragma unroll
    for (int nti = 0; nti < 4; ++nti) {
        const int nt = wv * 4 + nti;
        const int ncol = nt * 16 + mrow;

        const bf16x8 cwh = *(const bf16x8*)(cwhi + ncol * 32 + 8 * q);
        const bf16x8 cwl = *(const bf16x8*)(cwlo + ncol * 32 + 8 * q);

        u32 nxt[8];
        if (!LIFT && nti < 3) {
            const int ncoln = (nt + 1) * 16 + mrow;
            #pragma unroll
            for (int j = 0; j < 8; ++j)
                nxt[j] = xbp[(size_t)(8 * q + j) * NPIX + ncoln];
        }

        bf16x8 xh, xl;
        #pragma unroll
        for (int j = 0; j < 8; ++j) {
            if (LIFT) {
                const int k = 8 * q + j;
                const float v = (k < 3) ? xbf[(size_t)k * NPIX + ncol] : 0.f;
                const u16 hi = f2bf(v);
                xh[j] = (short)hi;
                xl[j] = (short)f2bf(v - bf2f(hi));
            } else {
                xh[j] = (short)(cur[j] & 0xFFFFu);
                xl[j] = (short)(cur[j] >> 16);
            }
        }

        float fpart = 0.f;
        #pragma unroll
        for (int mt = 0; mt < 2; ++mt) {
            f32x4 accT = {0.f, 0.f, 0.f, 0.f};
            f32x4 accW = {0.f, 0.f, 0.f, 0.f};
            accT = MFMA16(aThi[mt], cwh, accT);
            accT = MFMA16(aThi[mt], cwl, accT);
            accT = MFMA16(aTlo[mt], cwh, accT);
            accW = MFMA16(aWhi[mt], xh, accW);
            accW = MFMA16(aWhi[mt], xl, accW);
            accW = MFMA16(aWlo[mt], xh, accW);
            const f32x4 acc = accT + accW;
            if (FINAL) {
                #pragma unroll
                for (int i = 0; i < 4; ++i)
                    fpart += gelu_fast(acc[i]) * pwv[mt * 4 + i];
            } else {
                #pragma unroll
                for (int i = 0; i < 4; ++i) {
                    const int c = mt * 16 + q * 4 + i;
                    const float gl = gelu_fast(acc[i]);
                    dstp[((size_t)gb * NC + c) * NPIX + h * NW + ncol] = packsplit(gl);
                    if (PRODY) {
                        const u16 hi = f2bf(gl);
                        Ghi[c * 264 + ncol] = hi;
                        Glo[c * 264 + ncol] = f2bf(gl - bf2f(hi));
                    }
                }
            }
        }
        if (FINAL) {
            fpart += __shfl_xor(fpart, 16);
            fpart += __shfl_xor(fpart, 32);
            if (q == 0) {
                dstf[(((size_t)b * 4 + o) * NH + h) * NW + nt * 16 + mrow] = fpart + pb;
            }
        }

        if (!LIFT && nti < 3) {
            #pragma unroll
            for (int j = 0; j < 8; ++j) cur[j] = nxt[j];
        }
    }

    // ---- appended (PRODY): next layer's row-DFT for this (h, gb) ----
    if (PRODY) {
        __syncthreads();
        const int mt1 = wv >> 1, nt1 = wv & 1;   // 4 waves = 2x2 tiles
        f32x4 yA = {}, yB = {}, yC = {};
        #pragma unroll
        for (int ks = 0; ks < 8; ++ks) {
            const int ao = (mt1 * 16 + mrow) * 264 + ks * 32 + q * 8;
            const bf16x8 gh = *(const bf16x8*)&Ghi[ao];
            const bf16x8 gl = *(const bf16x8*)&Glo[ao];
            const int bo = (nt1 * 16 + mrow) * 256 + ks * 32 + q * 8;
            const bf16x8 bh = *(const bf16x8*)(ebhi + bo);
            const bf16x8 bl = *(const bf16x8*)(eblo + bo);
            yA = MFMA16(gh, bh, yA);
            yB = MFMA16(gh, bl, yB);
            yC = MFMA16(gl, bh, yC);
        }
        const f32x4 yacc = yA + yB + yC;
        #pragma unroll
        for (int r = 0; r < 4; ++r) {
            const int c = mt1 * 16 + q * 4 + r;
            const int combo = nt1 * 16 + mrow;
            Ypks[c * 32 + combo] = packsplit(yacc[r]);
        }
        __syncthreads();
        u32* yout = ypk + ((size_t)gb * 256 + h) * 1024;
        #pragma unroll
        for (int i = 0; i < 4; ++i)
            yout[i * 256 + tid] = Ypks[i * 256 + tid];
    }
}

// ---------------------------------------------------------------------------
extern "C" void kernel_launch(void* const* d_in, const int* in_sizes, int n_in,
                              void* d_out, int out_size, void* d_ws, size_t ws_size,
                              hipStream_t stream)
{
    const float* x      = (const float*)d_in[0];
    const float* lift_w = (const float*)d_in[1];
    const float* lift_b = (const float*)d_in[2];
    const float* wr     = (const float*)d_in[3];
    const float* wi     = (const float*)d_in[4];
    const float* byp_w  = (const float*)d_in[5];
    const float* byp_b  = (const float*)d_in[6];
    const float* proj_w = (const float*)d_in[7];
    const float* proj_b = (const float*)d_in[8];
    float* ws  = (float*)d_ws;

    const int G = 2;

    // ws: [cw/eb tables 16384 fl][zlift 65536][ylift 1M u32][y 2M u32]
    //     [zred G*ZG][zmix G*ZG][bufA][bufB]
    u16* cwhi = (u16*)ws;
    u16* cwlo = cwhi + 8192;
    u16* ebhi = cwlo + 8192;
    u16* eblo = ebhi + 8192;
    float* zlift = ws + 16384;
    u32* ylift = (u32*)(zlift + 65536);                      // 4*256*1024
    u32* y     = ylift + (size_t)4 * 256 * 1024;             // 8*256*1024
    float* zred = (float*)(y + (size_t)G * NB * 256 * 1024);
    float* zmix = zred + (size_t)G * ZG;
    u32* bufA = (u32*)(zmix + (size_t)G * ZG);
    u32* bufB = bufA + (size_t)G * NP;

    tab_prep<<<64, 256, 0, stream>>>(cwhi, cwlo, ebhi, eblo);

    // lift spectrum is o-independent: stage-1 + stage-2 once
    s1_lift<<<dim3(NC, NB, 4), 256, 0, stream>>>(x, lift_w, lift_b, ebhi, eblo, ylift);
    s2_kernel<<<dim3(NC, NB), 256, 0, stream>>>(ylift, ebhi, eblo, zlift);

    for (int o0 = 0; o0 < 4; o0 += G) {
        const u32* rd = nullptr;
        u32* wrbuf = bufA;
        for (int n = 0; n < 4; ++n) {
            const bool lift = (n == 0);
            const bool fin  = (n == 3);

            if (!lift)
                s2_kernel<<<dim3(NC, G * NB), 256, 0, stream>>>(y, ebhi, eblo, zred);

            mix_kernel<<<dim3(NC, 4, G), 256, 0, stream>>>(
                lift ? zlift : zred, zmix, wr, wi, o0, n, lift ? 0 : 1);

            dim3 igrid(NH, G * NB);
            if (fin) {
                inv_kernel<false, true, false><<<igrid, 256, 0, stream>>>(
                    zmix, rd, byp_w, byp_b, lift_w, lift_b, proj_w, proj_b,
                    cwhi, cwlo, ebhi, eblo, y, d_out, o0, n);
            } else if (lift) {
                inv_kernel<true, false, true><<<igrid, 256, 0, stream>>>(
                    zmix, x, byp_w, byp_b, lift_w, lift_b, proj_w, proj_b,
                    cwhi, cwlo, ebhi, eblo, y, wrbuf, o0, n);
            } else {
                inv_kernel<false, false, true><<<igrid, 256, 0, stream>>>(
                    zmix, rd, byp_w, byp_b, lift_w, lift_b, proj_w, proj_b,
                    cwhi, cwlo, ebhi, eblo, y, wrbuf, o0, n);
            }
            rd = wrbuf;
            wrbuf = (wrbuf == bufA) ? bufB : bufA;
        }
    }
}

// Round 6
// 497.419 us; speedup vs baseline: 1.7696x; 1.0028x over previous
//
#include <hip/hip_runtime.h>
#include <hip/hip_bf16.h>

#define NB 4      // batch
#define NC 32     // width (channels)
#define NH 256
#define NW 256
#define NM 16     // modes per dim
constexpr int NPIX = NH * NW;                 // 65536
constexpr int NP = NB * NC * NPIX;            // elements per per-o tensor (u32-packed)
constexpr int ZG = NB * NC * NM * NM * 2;     // floats per g for zred/zmix

typedef short bf16x8 __attribute__((ext_vector_type(8)));
typedef float f32x4  __attribute__((ext_vector_type(4)));
typedef unsigned short u16;
typedef unsigned int u32;

#define MFMA16(a, b, c) __builtin_amdgcn_mfma_f32_16x16x32_bf16(a, b, c, 0, 0, 0)

// HW RTNE f32->bf16 (v_cvt_pk_bf16_f32 via compiler; m240: casts compile well,
// do NOT hand-write the asm). Replaces the 4-op software round-to-nearest.
__device__ __forceinline__ u16 f2bf(float f) {
    const __hip_bfloat16 h = __float2bfloat16(f);
    return __builtin_bit_cast(u16, h);
}
__device__ __forceinline__ float bf2f(u16 h) {
    return __uint_as_float(((unsigned)h) << 16);
}
// pack fp32 -> (hi bf16) | (lo bf16 << 16); consumers use exactly hi+lo
__device__ __forceinline__ u32 packsplit(float f) {
    const u16 hi = f2bf(f);
    const u16 lo = f2bf(f - bf2f(hi));
    return (u32)hi | ((u32)lo << 16);
}

// fast erf (A&S 7.1.26, |err| <= 1.5e-7) based exact-GELU
__device__ __forceinline__ float gelu_fast(float v) {
    const float ax = fabsf(v) * 0.70710678118654752f;
    const float t = __builtin_amdgcn_rcpf(1.0f + 0.3275911f * ax);
    const float y = t * (0.254829592f + t * (-0.284496736f + t * (1.421413741f +
                    t * (-1.453152027f + t * 1.061405429f))));
    const float e = __expf(-ax * ax);
    float er = 1.0f - y * e;
    er = copysignf(er, v);
    return 0.5f * v * (1.0f + er);
}

// ---------------------------------------------------------------------------
// Table prep: cw (inv B-operand, [n=256][k=32]) and eb (fwd DFT matrix,
// [row=32][w=256], scaled 1/16; applied twice -> 1/256 ortho norm).
// ---------------------------------------------------------------------------
__global__ __launch_bounds__(256) void tab_prep(
    u16* __restrict__ cwhi, u16* __restrict__ cwlo,
    u16* __restrict__ ebhi, u16* __restrict__ eblo)
{
    const int id = blockIdx.x * 256 + threadIdx.x;   // 0..16383
    if (id < 8192) {
        const int nn = id >> 5, k = id & 31;
        const int m = ((k & 15) * nn) & 255;
        float s, c;
        sincospif((float)m * (2.0f / 256.0f), &s, &c);
        const float v = (k < 16) ? c : s;
        const u16 hi = f2bf(v);
        cwhi[id] = hi;
        cwlo[id] = f2bf(v - bf2f(hi));
    } else {
        const int id2 = id - 8192;
        const int row = id2 >> 8, w = id2 & 255;
        const int m = ((row & 15) * w) & 255;
        float s, c;
        sincospif((float)m * (2.0f / 256.0f), &s, &c);
        const float v = 0.0625f * ((row < 16) ? c : s);
        const u16 hi = f2bf(v);
        ebhi[id2] = hi;
        eblo[id2] = f2bf(v - bf2f(hi));
    }
}

// ---------------------------------------------------------------------------
// Lift stage 1 (once per call): Y_lift[b][h][c*32+combo] (packed u32) from x.
// ---------------------------------------------------------------------------
__global__ __launch_bounds__(256) void s1_lift(
    const float* __restrict__ src,      // x[B,3,H,W]
    const float* __restrict__ lift_w,
    const float* __restrict__ lift_b,
    const u16* __restrict__ ebhi,
    const u16* __restrict__ eblo,
    u32* __restrict__ ypk)              // [b][h][1024]
{
    __shared__ u32 TrPk[64][33];        // [h-local][combo]

    const int tid = threadIdx.x;
    const int c  = blockIdx.x;
    const int b  = blockIdx.y;
    const int hq = blockIdx.z;
    const int wv = tid >> 6, lane = tid & 63;
    const int mrow = lane & 15, q = lane >> 4;
    const int hbase = hq * 64 + wv * 16;

    const float lw0 = lift_w[c * 3 + 0], lw1 = lift_w[c * 3 + 1], lw2 = lift_w[c * 3 + 2];
    const float lb = lift_b[c];
    const float* sb = src + (size_t)b * 3 * NPIX;

    f32x4 acc[2] = {};
    for (int ks = 0; ks < 8; ++ks) {
        bf16x8 bh[2], bl[2];
        #pragma unroll
        for (int nt = 0; nt < 2; ++nt) {
            const int off = (nt * 16 + mrow) * 256 + ks * 32 + q * 8;
            bh[nt] = *(const bf16x8*)(ebhi + off);
            bl[nt] = *(const bf16x8*)(eblo + off);
        }
        const float* xp = sb + (size_t)(hbase + mrow) * NW + ks * 32 + q * 8;
        const float4 p0a = *(const float4*)(xp);
        const float4 p0b = *(const float4*)(xp + 4);
        const float4 p1a = *(const float4*)(xp + NPIX);
        const float4 p1b = *(const float4*)(xp + NPIX + 4);
        const float4 p2a = *(const float4*)(xp + 2 * NPIX);
        const float4 p2b = *(const float4*)(xp + 2 * NPIX + 4);
        float v[8];
        v[0] = lw0 * p0a.x + lw1 * p1a.x + lw2 * p2a.x + lb;
        v[1] = lw0 * p0a.y + lw1 * p1a.y + lw2 * p2a.y + lb;
        v[2] = lw0 * p0a.z + lw1 * p1a.z + lw2 * p2a.z + lb;
        v[3] = lw0 * p0a.w + lw1 * p1a.w + lw2 * p2a.w + lb;
        v[4] = lw0 * p0b.x + lw1 * p1b.x + lw2 * p2b.x + lb;
        v[5] = lw0 * p0b.y + lw1 * p1b.y + lw2 * p2b.y + lb;
        v[6] = lw0 * p0b.z + lw1 * p1b.z + lw2 * p2b.z + lb;
        v[7] = lw0 * p0b.w + lw1 * p1b.w + lw2 * p2b.w + lb;
        bf16x8 xh, xl;
        #pragma unroll
        for (int j = 0; j < 8; ++j) {
            const u16 hi = f2bf(v[j]);
            xh[j] = (short)hi;
            xl[j] = (short)f2bf(v[j] - bf2f(hi));
        }
        #pragma unroll
        for (int nt = 0; nt < 2; ++nt) {
            acc[nt] = MFMA16(xh, bh[nt], acc[nt]);
            acc[nt] = MFMA16(xh, bl[nt], acc[nt]);
            acc[nt] = MFMA16(xl, bh[nt], acc[nt]);
        }
    }

    // C-layout: acc[nt][r] at (h-local = wv*16 + q*4 + r, combo = nt*16 + mrow)
    #pragma unroll
    for (int nt = 0; nt < 2; ++nt) {
        #pragma unroll
        for (int r = 0; r < 4; ++r)
            TrPk[wv * 16 + q * 4 + r][nt * 16 + mrow] = packsplit(acc[nt][r]);
    }
    __syncthreads();

    #pragma unroll
    for (int i = 0; i < 8; ++i) {
        const int idx = i * 256 + tid;
        const int hl = idx >> 5, combo = idx & 31;
        ypk[((size_t)b * 256 + hq * 64 + hl) * 1024 + c * 32 + combo] = TrPk[hl][combo];
    }
}

// ---------------------------------------------------------------------------
// s2: column-DFT P[kc][wc] = sum_h EB[kc][h] * Y[wc][h] + quadrant combine.
// ---------------------------------------------------------------------------
__global__ __launch_bounds__(256) void s2_kernel(
    const u32* __restrict__ ypk,
    const u16* __restrict__ ebhi,
    const u16* __restrict__ eblo,
    float* __restrict__ zred)
{
    __shared__ u32 Yl[256][33];         // [h][combo], pad 33
    __shared__ float P[32][33];

    const int tid = threadIdx.x;
    const int c  = blockIdx.x;
    const int gb = blockIdx.y;
    const int wv = tid >> 6, lane = tid & 63;
    const int mrow = lane & 15, q = lane >> 4;

    #pragma unroll
    for (int i = 0; i < 32; ++i) {
        const int idx = i * 256 + tid;
        const int h = idx >> 5, combo = idx & 31;
        Yl[h][combo] = ypk[((size_t)gb * 256 + h) * 1024 + c * 32 + combo];
    }
    __syncthreads();

    const int mt2 = wv >> 1, nt2 = wv & 1;
    const int wc = nt2 * 16 + mrow;
    f32x4 p = {};
    for (int ks = 0; ks < 8; ++ks) {
        const int aoff = (mt2 * 16 + mrow) * 256 + ks * 32 + q * 8;
        const bf16x8 ah = *(const bf16x8*)(ebhi + aoff);
        const bf16x8 al = *(const bf16x8*)(eblo + aoff);
        bf16x8 yh, yl;
        #pragma unroll
        for (int j = 0; j < 8; ++j) {
            const u32 v = Yl[ks * 32 + q * 8 + j][wc];
            yh[j] = (short)(v & 0xFFFFu);
            yl[j] = (short)(v >> 16);
        }
        p = MFMA16(ah, yh, p);
        p = MFMA16(ah, yl, p);
        p = MFMA16(al, yh, p);
    }
    #pragma unroll
    for (int r = 0; r < 4; ++r)
        P[mt2 * 16 + q * 4 + r][wc] = p[r];
    __syncthreads();

    // combine: Zr = Pcc - Pss, Zi = -(Pcs + Psc)
    const int k = tid >> 4, l = tid & 15;
    const float zr = P[k][l] - P[16 + k][16 + l];
    const float zi = -(P[k][16 + l] + P[16 + k][l]);
    const int idx = (gb * NC + c) * 256 + tid;
    zred[idx * 2 + 0] = zr;
    zred[idx * 2 + 1] = zi;
}

// ---------------------------------------------------------------------------
// Mode mix: grid (oc=32, mq=4, g=G); block 256.
// ---------------------------------------------------------------------------
__global__ __launch_bounds__(256) void mix_kernel(
    const float* __restrict__ zred,
    float* __restrict__ zmix,
    const float* __restrict__ wr,
    const float* __restrict__ wi,
    int o0, int n, int zgmul)
{
    __shared__ float ps[4][NB][64][2];
    const int tid = threadIdx.x;
    const int oc = blockIdx.x, mq = blockIdx.y, g = blockIdx.z;
    const int o = o0 + g, zg = zgmul * g;
    const int ichunk = tid >> 6, ml = tid & 63;
    const int mode = mq * 64 + ml;

    const float* wrb = wr + (size_t)(o * 4 + n) * NC * NC * 256;
    const float* wib = wi + (size_t)(o * 4 + n) * NC * NC * 256;

    float orr[NB] = {0.f, 0.f, 0.f, 0.f};
    float oii[NB] = {0.f, 0.f, 0.f, 0.f};

    #pragma unroll
    for (int ii = 0; ii < 8; ++ii) {
        const int i = ichunk * 8 + ii;
        const float wrv = wrb[(i * NC + oc) * 256 + mode];
        const float wiv = wib[(i * NC + oc) * 256 + mode];
        #pragma unroll
        for (int b = 0; b < NB; ++b) {
            const float2 z = *(const float2*)&zred[(((zg * NB + b) * NC + i) * 256 + mode) * 2];
            orr[b] += z.x * wrv - z.y * wiv;
            oii[b] += z.x * wiv + z.y * wrv;
        }
    }
    #pragma unroll
    for (int b = 0; b < NB; ++b) {
        ps[ichunk][b][ml][0] = orr[b];
        ps[ichunk][b][ml][1] = oii[b];
    }
    __syncthreads();

    const int b2 = tid >> 6, ml2 = tid & 63;
    float re = 0.f, im = 0.f;
    #pragma unroll
    for (int ic = 0; ic < 4; ++ic) {
        re += ps[ic][b2][ml2][0];
        im += ps[ic][b2][ml2][1];
    }
    const int oidx = ((g * NB + b2) * NC + oc) * 256 + mq * 64 + ml2;
    zmix[oidx * 2 + 0] = re;
    zmix[oidx * 2 + 1] = im;
}

// ---------------------------------------------------------------------------
// Inverse transform + bypass + GELU (+ projection if FINAL) + next layer's
// row-DFT Y if PRODY.  Body = round-5 verified form (50688B LDS, 3 blocks/CU,
// depth-1 prefetch, split acc chains); conversions now use the HW bf16
// converter via f2bf.
// ---------------------------------------------------------------------------
template<bool LIFT, bool FINAL, bool PRODY>
__global__ __launch_bounds__(256) void inv_kernel(
    const float* __restrict__ zmix,
    const void* __restrict__ srcv,      // LIFT ? float x : u32 xb
    const float* __restrict__ byp_w,
    const float* __restrict__ byp_b,
    const float* __restrict__ lift_w,
    const float* __restrict__ lift_b,
    const float* __restrict__ proj_w,
    const float* __restrict__ proj_b,
    const u16* __restrict__ cwhi,
    const u16* __restrict__ cwlo,
    const u16* __restrict__ ebhi,
    const u16* __restrict__ eblo,
    u32* __restrict__ ypk,              // [gb][h][1024] (PRODY)
    void* __restrict__ dstv,            // FINAL ? float out : u32 xb
    int o0, int n)
{
    __shared__ float2 tw[256];
    __shared__ u16 Thi[NC * 40], Tlo[NC * 40];
    __shared__ u16 Whi[NC * 40], Wlo[NC * 40];
    __shared__ float bbl[NC];
    __shared__ float bweffs[NC * 3];
    __shared__ u16 Ghi[PRODY ? 32 * 264 : 1];
    __shared__ u16 Glo[PRODY ? 32 * 264 : 1];
    __shared__ u32 Ypks[PRODY ? 1024 : 1];

    const int tid = threadIdx.x;
    const int h = blockIdx.x;
    const int gb = blockIdx.y;
    const int g = gb >> 2, b = gb & 3;
    const int o = o0 + g;

    {
        float s, cs;
        sincospif((float)tid * (2.0f / 256.0f), &s, &cs);
        tw[tid] = make_float2(cs, s);
    }

    const float* bwp = byp_w + (size_t)(o * 4 + n) * NC * NC;
    const float* bbp = byp_b + (o * 4 + n) * NC;

    if (LIFT) {
        if (tid < 96) {
            const int oc = tid / 3, j = tid % 3;
            float s = 0.f;
            for (int ic = 0; ic < NC; ++ic) s += bwp[oc * NC + ic] * lift_w[ic * 3 + j];
            bweffs[oc * 3 + j] = s;
        } else if (tid < 128) {
            const int oc = tid - 96;
            float s = bbp[oc];
            for (int ic = 0; ic < NC; ++ic) s += bwp[oc * NC + ic] * lift_b[ic];
            bbl[oc] = s;
        }
    } else {
        if (tid < NC) bbl[tid] = bbp[tid];
    }
    __syncthreads();

    for (int idx = tid; idx < NC * NC; idx += 256) {
        const int c = idx >> 5, ic = idx & 31;
        float v;
        if (LIFT) v = (ic < 3) ? bweffs[c * 3 + ic] : 0.f;
        else      v = bwp[idx];
        const u16 hi = f2bf(v);
        Whi[c * 40 + ic] = hi;
        Wlo[c * 40 + ic] = f2bf(v - bf2f(hi));
    }

    // phase A: T[c][l] from zmix; bias folded into T[c][0]
    #pragma unroll
    for (int rep = 0; rep < 2; ++rep) {
        const int it = rep * 256 + tid;
        const int c = it >> 4, l = it & 15;
        const float sl = (l == 0 ? 1.0f : 2.0f) / 256.0f;
        const float* zp = zmix + ((size_t)(gb * NC + c) * 256 + l) * 2;
        float tr = 0.f, ti = 0.f;
        int m = 0;
        #pragma unroll
        for (int k = 0; k < NM; ++k) {
            const float2 z = *(const float2*)(zp + k * 32);
            const float2 t = tw[m];
            tr += z.x * t.x - z.y * t.y;
            ti += z.x * t.y + z.y * t.x;
            m = (m + h) & 255;
        }
        tr *= sl; ti *= sl;
        if (l == 0) tr += bbl[c];
        const u16 rh = f2bf(tr);
        Thi[c * 40 + l] = rh;
        Tlo[c * 40 + l] = f2bf(tr - bf2f(rh));
        const float nti_ = -ti;
        const u16 ih = f2bf(nti_);
        Thi[c * 40 + 16 + l] = ih;
        Tlo[c * 40 + 16 + l] = f2bf(nti_ - bf2f(ih));
    }
    __syncthreads();

    const int lane = tid & 63, wv = tid >> 6;
    const int mrow = lane & 15, q = lane >> 4;

    bf16x8 aThi[2], aTlo[2], aWhi[2], aWlo[2];
    #pragma unroll
    for (int mt = 0; mt < 2; ++mt) {
        const int ro = (mt * 16 + mrow) * 40 + 8 * q;
        aThi[mt] = *(const bf16x8*)&Thi[ro];
        aTlo[mt] = *(const bf16x8*)&Tlo[ro];
        aWhi[mt] = *(const bf16x8*)&Whi[ro];
        aWlo[mt] = *(const bf16x8*)&Wlo[ro];
    }

    float pwv[8];
    float pb = 0.f;
    if (FINAL) {
        #pragma unroll
        for (int mt = 0; mt < 2; ++mt)
            #pragma unroll
            for (int i = 0; i < 4; ++i)
                pwv[mt * 4 + i] = proj_w[mt * 16 + q * 4 + i];
        pb = proj_b[0];
    }

    const float* xbf = LIFT ? (const float*)srcv + (size_t)b * 3 * NPIX + h * NW : nullptr;
    const u32*   xbp = LIFT ? nullptr : (const u32*)srcv + (size_t)gb * NC * NPIX + h * NW;
    u32*   dstp = (u32*)dstv;
    float* dstf = (float*)dstv;

    // depth-1 prefetch of the bypass row (non-LIFT path only)
    u32 cur[8];
    if (!LIFT) {
        const int ncol0 = (wv * 4 + 0) * 16 + mrow;
        #pragma unroll
        for (int j = 0; j < 8; ++j)
            cur[j] = xbp[(size_t)(8 * q + j) * NPIX + ncol0];
    }

    #pragma unroll
    for (int nti = 0; nti < 4; ++nti) {
        const int nt = wv * 4 + nti;
        const int ncol = nt * 16 + mrow;

        const bf16x8 cwh = *(const bf16x8*)(cwhi + ncol * 32 + 8 * q);
        const bf16x8 cwl = *(const bf16x8*)(cwlo + ncol * 32 + 8 * q);

        u32 nxt[8];
        if (!LIFT && nti < 3) {
            const int ncoln = (nt + 1) * 16 + mrow;
            #pragma unroll
            for (int j = 0; j < 8; ++j)
                nxt[j] = xbp[(size_t)(8 * q + j) * NPIX + ncoln];
        }

        bf16x8 xh, xl;
        #pragma unroll
        for (int j = 0; j < 8; ++j) {
            if (LIFT) {
                const int k = 8 * q + j;
                const float v = (k < 3) ? xbf[(size_t)k * NPIX + ncol] : 0.f;
                const u16 hi = f2bf(v);
                xh[j] = (short)hi;
                xl[j] = (short)f2bf(v - bf2f(hi));
            } else {
                xh[j] = (short)(cur[j] & 0xFFFFu);
                xl[j] = (short)(cur[j] >> 16);
            }
        }

        float fpart = 0.f;
        #pragma unroll
        for (int mt = 0; mt < 2; ++mt) {
            f32x4 accT = {0.f, 0.f, 0.f, 0.f};
            f32x4 accW = {0.f, 0.f, 0.f, 0.f};
            accT = MFMA16(aThi[mt], cwh, accT);
            accT = MFMA16(aThi[mt], cwl, accT);
            accT = MFMA16(aTlo[mt], cwh, accT);
            accW = MFMA16(aWhi[mt], xh, accW);
            accW = MFMA16(aWhi[mt], xl, accW);
            accW = MFMA16(aWlo[mt], xh, accW);
            const f32x4 acc = accT + accW;
            if (FINAL) {
                #pragma unroll
                for (int i = 0; i < 4; ++i)
                    fpart += gelu_fast(acc[i]) * pwv[mt * 4 + i];
            } else {
                #pragma unroll
                for (int i = 0; i < 4; ++i) {
                    const int c = mt * 16 + q * 4 + i;
                    const float gl = gelu_fast(acc[i]);
                    dstp[((size_t)gb * NC + c) * NPIX + h * NW + ncol] = packsplit(gl);
                    if (PRODY) {
                        const u16 hi = f2bf(gl);
                        Ghi[c * 264 + ncol] = hi;
                        Glo[c * 264 + ncol] = f2bf(gl - bf2f(hi));
                    }
                }
            }
        }
        if (FINAL) {
            fpart += __shfl_xor(fpart, 16);
            fpart += __shfl_xor(fpart, 32);
            if (q == 0) {
                dstf[(((size_t)b * 4 + o) * NH + h) * NW + nt * 16 + mrow] = fpart + pb;
            }
        }

        if (!LIFT && nti < 3) {
            #pragma unroll
            for (int j = 0; j < 8; ++j) cur[j] = nxt[j];
        }
    }

    // ---- appended (PRODY): next layer's row-DFT for this (h, gb) ----
    if (PRODY) {
        __syncthreads();
        const int mt1 = wv >> 1, nt1 = wv & 1;   // 4 waves = 2x2 tiles
        f32x4 yA = {}, yB = {}, yC = {};
        #pragma unroll
        for (int ks = 0; ks < 8; ++ks) {
            const int ao = (mt1 * 16 + mrow) * 264 + ks * 32 + q * 8;
            const bf16x8 gh = *(const bf16x8*)&Ghi[ao];
            const bf16x8 gl = *(const bf16x8*)&Glo[ao];
            const int bo = (nt1 * 16 + mrow) * 256 + ks * 32 + q * 8;
            const bf16x8 bh = *(const bf16x8*)(ebhi + bo);
            const bf16x8 bl = *(const bf16x8*)(eblo + bo);
            yA = MFMA16(gh, bh, yA);
            yB = MFMA16(gh, bl, yB);
            yC = MFMA16(gl, bh, yC);
        }
        const f32x4 yacc = yA + yB + yC;
        #pragma unroll
        for (int r = 0; r < 4; ++r) {
            const int c = mt1 * 16 + q * 4 + r;
            const int combo = nt1 * 16 + mrow;
            Ypks[c * 32 + combo] = packsplit(yacc[r]);
        }
        __syncthreads();
        u32* yout = ypk + ((size_t)gb * 256 + h) * 1024;
        #pragma unroll
        for (int i = 0; i < 4; ++i)
            yout[i * 256 + tid] = Ypks[i * 256 + tid];
    }
}

// ---------------------------------------------------------------------------
extern "C" void kernel_launch(void* const* d_in, const int* in_sizes, int n_in,
                              void* d_out, int out_size, void* d_ws, size_t ws_size,
                              hipStream_t stream)
{
    const float* x      = (const float*)d_in[0];
    const float* lift_w = (const float*)d_in[1];
    const float* lift_b = (const float*)d_in[2];
    const float* wr     = (const float*)d_in[3];
    const float* wi     = (const float*)d_in[4];
    const float* byp_w  = (const float*)d_in[5];
    const float* byp_b  = (const float*)d_in[6];
    const float* proj_w = (const float*)d_in[7];
    const float* proj_b = (const float*)d_in[8];
    float* ws  = (float*)d_ws;

    // Runtime G: all 4 independent o-chains per dispatch if the workspace
    // allows (halves dispatch count + tail fraction); else verified G=2.
    auto need_bytes = [](int Gq) -> size_t {
        size_t bts = 0;
        bts += (size_t)4 * 8192 * sizeof(u16);          // cw/eb tables
        bts += (size_t)65536 * 4;                       // zlift
        bts += (size_t)4 * 256 * 1024 * 4;              // ylift
        bts += (size_t)Gq * NB * 256 * 1024 * 4;        // y
        bts += (size_t)Gq * ZG * 4 * 2;                 // zred + zmix
        bts += (size_t)Gq * NP * 4 * 2;                 // bufA + bufB
        return bts;
    };
    const int G = (ws_size >= need_bytes(4)) ? 4 : 2;

    // ws: [cw/eb tables 16384 fl][zlift 65536][ylift 1M u32][y G*1M u32]
    //     [zred G*ZG][zmix G*ZG][bufA][bufB]
    u16* cwhi = (u16*)ws;
    u16* cwlo = cwhi + 8192;
    u16* ebhi = cwlo + 8192;
    u16* eblo = ebhi + 8192;
    float* zlift = ws + 16384;
    u32* ylift = (u32*)(zlift + 65536);                      // 4*256*1024
    u32* y     = ylift + (size_t)4 * 256 * 1024;             // G*4*256*1024
    float* zred = (float*)(y + (size_t)G * NB * 256 * 1024);
    float* zmix = zred + (size_t)G * ZG;
    u32* bufA = (u32*)(zmix + (size_t)G * ZG);
    u32* bufB = bufA + (size_t)G * NP;

    tab_prep<<<64, 256, 0, stream>>>(cwhi, cwlo, ebhi, eblo);

    // lift spectrum is o-independent: stage-1 + stage-2 once
    s1_lift<<<dim3(NC, NB, 4), 256, 0, stream>>>(x, lift_w, lift_b, ebhi, eblo, ylift);
    s2_kernel<<<dim3(NC, NB), 256, 0, stream>>>(ylift, ebhi, eblo, zlift);

    for (int o0 = 0; o0 < 4; o0 += G) {
        const u32* rd = nullptr;
        u32* wrbuf = bufA;
        for (int n = 0; n < 4; ++n) {
            const bool lift = (n == 0);
            const bool fin  = (n == 3);

            if (!lift)
                s2_kernel<<<dim3(NC, G * NB), 256, 0, stream>>>(y, ebhi, eblo, zred);

            mix_kernel<<<dim3(NC, 4, G), 256, 0, stream>>>(
                lift ? zlift : zred, zmix, wr, wi, o0, n, lift ? 0 : 1);

            dim3 igrid(NH, G * NB);
            if (fin) {
                inv_kernel<false, true, false><<<igrid, 256, 0, stream>>>(
                    zmix, rd, byp_w, byp_b, lift_w, lift_b, proj_w, proj_b,
                    cwhi, cwlo, ebhi, eblo, y, d_out, o0, n);
            } else if (lift) {
                inv_kernel<true, false, true><<<igrid, 256, 0, stream>>>(
                    zmix, x, byp_w, byp_b, lift_w, lift_b, proj_w, proj_b,
                    cwhi, cwlo, ebhi, eblo, y, wrbuf, o0, n);
            } else {
                inv_kernel<false, false, true><<<igrid, 256, 0, stream>>>(
                    zmix, rd, byp_w, byp_b, lift_w, lift_b, proj_w, proj_b,
                    cwhi, cwlo, ebhi, eblo, y, wrbuf, o0, n);
            }
            rd = wrbuf;
            wrbuf = (wrbuf == bufA) ? bufB : bufA;
        }
    }
}

// Round 7
// 445.796 us; speedup vs baseline: 1.9745x; 1.1158x over previous
//
#include <hip/hip_runtime.h>
#include <hip/hip_bf16.h>

#define NB 4      // batch
#define NC 32     // width (channels)
#define NH 256
#define NW 256
#define NM 16     // modes per dim
constexpr int NPIX = NH * NW;                 // 65536
constexpr int NP = NB * NC * NPIX;            // elements per per-o tensor (u32-packed)
constexpr int ZG = NB * NC * NM * NM * 2;     // floats per g for zred/zmix

typedef short bf16x8 __attribute__((ext_vector_type(8)));
typedef float f32x4  __attribute__((ext_vector_type(4)));
typedef unsigned short u16;
typedef unsigned int u32;

#define MFMA16(a, b, c) __builtin_amdgcn_mfma_f32_16x16x32_bf16(a, b, c, 0, 0, 0)

// HW RTNE f32->bf16 (v_cvt via compiler).
__device__ __forceinline__ u16 f2bf(float f) {
    const __hip_bfloat16 h = __float2bfloat16(f);
    return __builtin_bit_cast(u16, h);
}
__device__ __forceinline__ float bf2f(u16 h) {
    return __uint_as_float(((unsigned)h) << 16);
}
// pack fp32 -> (hi bf16) | (lo bf16 << 16); consumers use exactly hi+lo
__device__ __forceinline__ u32 packsplit(float f) {
    const u16 hi = f2bf(f);
    const u16 lo = f2bf(f - bf2f(hi));
    return (u32)hi | ((u32)lo << 16);
}

// fast erf (A&S 7.1.26, |err| <= 1.5e-7) based exact-GELU
__device__ __forceinline__ float gelu_fast(float v) {
    const float ax = fabsf(v) * 0.70710678118654752f;
    const float t = __builtin_amdgcn_rcpf(1.0f + 0.3275911f * ax);
    const float y = t * (0.254829592f + t * (-0.284496736f + t * (1.421413741f +
                    t * (-1.453152027f + t * 1.061405429f))));
    const float e = __expf(-ax * ax);
    float er = 1.0f - y * e;
    er = copysignf(er, v);
    return 0.5f * v * (1.0f + er);
}

// ---------------------------------------------------------------------------
// Table prep: cw (inv B-operand, [n=256][k=32]) and eb (fwd DFT matrix,
// [row=32][w=256], scaled 1/16; applied twice -> 1/256 ortho norm).
// ---------------------------------------------------------------------------
__global__ __launch_bounds__(256) void tab_prep(
    u16* __restrict__ cwhi, u16* __restrict__ cwlo,
    u16* __restrict__ ebhi, u16* __restrict__ eblo)
{
    const int id = blockIdx.x * 256 + threadIdx.x;   // 0..16383
    if (id < 8192) {
        const int nn = id >> 5, k = id & 31;
        const int m = ((k & 15) * nn) & 255;
        float s, c;
        sincospif((float)m * (2.0f / 256.0f), &s, &c);
        const float v = (k < 16) ? c : s;
        const u16 hi = f2bf(v);
        cwhi[id] = hi;
        cwlo[id] = f2bf(v - bf2f(hi));
    } else {
        const int id2 = id - 8192;
        const int row = id2 >> 8, w = id2 & 255;
        const int m = ((row & 15) * w) & 255;
        float s, c;
        sincospif((float)m * (2.0f / 256.0f), &s, &c);
        const float v = 0.0625f * ((row < 16) ? c : s);
        const u16 hi = f2bf(v);
        ebhi[id2] = hi;
        eblo[id2] = f2bf(v - bf2f(hi));
    }
}

// ---------------------------------------------------------------------------
// Lift stage 1 (once per call): Y_lift[b][h][c*32+combo] (packed u32) from x.
// ---------------------------------------------------------------------------
__global__ __launch_bounds__(256) void s1_lift(
    const float* __restrict__ src,      // x[B,3,H,W]
    const float* __restrict__ lift_w,
    const float* __restrict__ lift_b,
    const u16* __restrict__ ebhi,
    const u16* __restrict__ eblo,
    u32* __restrict__ ypk)              // [b][h][1024]
{
    __shared__ u32 TrPk[64][33];        // [h-local][combo]

    const int tid = threadIdx.x;
    const int c  = blockIdx.x;
    const int b  = blockIdx.y;
    const int hq = blockIdx.z;
    const int wv = tid >> 6, lane = tid & 63;
    const int mrow = lane & 15, q = lane >> 4;
    const int hbase = hq * 64 + wv * 16;

    const float lw0 = lift_w[c * 3 + 0], lw1 = lift_w[c * 3 + 1], lw2 = lift_w[c * 3 + 2];
    const float lb = lift_b[c];
    const float* sb = src + (size_t)b * 3 * NPIX;

    f32x4 acc[2] = {};
    for (int ks = 0; ks < 8; ++ks) {
        bf16x8 bh[2], bl[2];
        #pragma unroll
        for (int nt = 0; nt < 2; ++nt) {
            const int off = (nt * 16 + mrow) * 256 + ks * 32 + q * 8;
            bh[nt] = *(const bf16x8*)(ebhi + off);
            bl[nt] = *(const bf16x8*)(eblo + off);
        }
        const float* xp = sb + (size_t)(hbase + mrow) * NW + ks * 32 + q * 8;
        const float4 p0a = *(const float4*)(xp);
        const float4 p0b = *(const float4*)(xp + 4);
        const float4 p1a = *(const float4*)(xp + NPIX);
        const float4 p1b = *(const float4*)(xp + NPIX + 4);
        const float4 p2a = *(const float4*)(xp + 2 * NPIX);
        const float4 p2b = *(const float4*)(xp + 2 * NPIX + 4);
        float v[8];
        v[0] = lw0 * p0a.x + lw1 * p1a.x + lw2 * p2a.x + lb;
        v[1] = lw0 * p0a.y + lw1 * p1a.y + lw2 * p2a.y + lb;
        v[2] = lw0 * p0a.z + lw1 * p1a.z + lw2 * p2a.z + lb;
        v[3] = lw0 * p0a.w + lw1 * p1a.w + lw2 * p2a.w + lb;
        v[4] = lw0 * p0b.x + lw1 * p1b.x + lw2 * p2b.x + lb;
        v[5] = lw0 * p0b.y + lw1 * p1b.y + lw2 * p2b.y + lb;
        v[6] = lw0 * p0b.z + lw1 * p1b.z + lw2 * p2b.z + lb;
        v[7] = lw0 * p0b.w + lw1 * p1b.w + lw2 * p2b.w + lb;
        bf16x8 xh, xl;
        #pragma unroll
        for (int j = 0; j < 8; ++j) {
            const u16 hi = f2bf(v[j]);
            xh[j] = (short)hi;
            xl[j] = (short)f2bf(v[j] - bf2f(hi));
        }
        #pragma unroll
        for (int nt = 0; nt < 2; ++nt) {
            acc[nt] = MFMA16(xh, bh[nt], acc[nt]);
            acc[nt] = MFMA16(xh, bl[nt], acc[nt]);
            acc[nt] = MFMA16(xl, bh[nt], acc[nt]);
        }
    }

    // C-layout: acc[nt][r] at (h-local = wv*16 + q*4 + r, combo = nt*16 + mrow)
    #pragma unroll
    for (int nt = 0; nt < 2; ++nt) {
        #pragma unroll
        for (int r = 0; r < 4; ++r)
            TrPk[wv * 16 + q * 4 + r][nt * 16 + mrow] = packsplit(acc[nt][r]);
    }
    __syncthreads();

    #pragma unroll
    for (int i = 0; i < 8; ++i) {
        const int idx = i * 256 + tid;
        const int hl = idx >> 5, combo = idx & 31;
        ypk[((size_t)b * 256 + hq * 64 + hl) * 1024 + c * 32 + combo] = TrPk[hl][combo];
    }
}

// ---------------------------------------------------------------------------
// s2: column-DFT P[kc][wc] = sum_h EB[kc][h] * Y[wc][h] + quadrant combine.
// ---------------------------------------------------------------------------
__global__ __launch_bounds__(256) void s2_kernel(
    const u32* __restrict__ ypk,
    const u16* __restrict__ ebhi,
    const u16* __restrict__ eblo,
    float* __restrict__ zred)
{
    __shared__ u32 Yl[256][33];         // [h][combo], pad 33
    __shared__ float P[32][33];

    const int tid = threadIdx.x;
    const int c  = blockIdx.x;
    const int gb = blockIdx.y;
    const int wv = tid >> 6, lane = tid & 63;
    const int mrow = lane & 15, q = lane >> 4;

    #pragma unroll
    for (int i = 0; i < 32; ++i) {
        const int idx = i * 256 + tid;
        const int h = idx >> 5, combo = idx & 31;
        Yl[h][combo] = ypk[((size_t)gb * 256 + h) * 1024 + c * 32 + combo];
    }
    __syncthreads();

    const int mt2 = wv >> 1, nt2 = wv & 1;
    const int wc = nt2 * 16 + mrow;
    f32x4 p = {};
    for (int ks = 0; ks < 8; ++ks) {
        const int aoff = (mt2 * 16 + mrow) * 256 + ks * 32 + q * 8;
        const bf16x8 ah = *(const bf16x8*)(ebhi + aoff);
        const bf16x8 al = *(const bf16x8*)(eblo + aoff);
        bf16x8 yh, yl;
        #pragma unroll
        for (int j = 0; j < 8; ++j) {
            const u32 v = Yl[ks * 32 + q * 8 + j][wc];
            yh[j] = (short)(v & 0xFFFFu);
            yl[j] = (short)(v >> 16);
        }
        p = MFMA16(ah, yh, p);
        p = MFMA16(ah, yl, p);
        p = MFMA16(al, yh, p);
    }
    #pragma unroll
    for (int r = 0; r < 4; ++r)
        P[mt2 * 16 + q * 4 + r][wc] = p[r];
    __syncthreads();

    // combine: Zr = Pcc - Pss, Zi = -(Pcs + Psc)
    const int k = tid >> 4, l = tid & 15;
    const float zr = P[k][l] - P[16 + k][16 + l];
    const float zi = -(P[k][16 + l] + P[16 + k][l]);
    const int idx = (gb * NC + c) * 256 + tid;
    zred[idx * 2 + 0] = zr;
    zred[idx * 2 + 1] = zi;
}

// ---------------------------------------------------------------------------
// Mode mix: grid (oc=32, mq=4, g=G); block 256.
// ---------------------------------------------------------------------------
__global__ __launch_bounds__(256) void mix_kernel(
    const float* __restrict__ zred,
    float* __restrict__ zmix,
    const float* __restrict__ wr,
    const float* __restrict__ wi,
    int o0, int n, int zgmul)
{
    __shared__ float ps[4][NB][64][2];
    const int tid = threadIdx.x;
    const int oc = blockIdx.x, mq = blockIdx.y, g = blockIdx.z;
    const int o = o0 + g, zg = zgmul * g;
    const int ichunk = tid >> 6, ml = tid & 63;
    const int mode = mq * 64 + ml;

    const float* wrb = wr + (size_t)(o * 4 + n) * NC * NC * 256;
    const float* wib = wi + (size_t)(o * 4 + n) * NC * NC * 256;

    float orr[NB] = {0.f, 0.f, 0.f, 0.f};
    float oii[NB] = {0.f, 0.f, 0.f, 0.f};

    #pragma unroll
    for (int ii = 0; ii < 8; ++ii) {
        const int i = ichunk * 8 + ii;
        const float wrv = wrb[(i * NC + oc) * 256 + mode];
        const float wiv = wib[(i * NC + oc) * 256 + mode];
        #pragma unroll
        for (int b = 0; b < NB; ++b) {
            const float2 z = *(const float2*)&zred[(((zg * NB + b) * NC + i) * 256 + mode) * 2];
            orr[b] += z.x * wrv - z.y * wiv;
            oii[b] += z.x * wiv + z.y * wrv;
        }
    }
    #pragma unroll
    for (int b = 0; b < NB; ++b) {
        ps[ichunk][b][ml][0] = orr[b];
        ps[ichunk][b][ml][1] = oii[b];
    }
    __syncthreads();

    const int b2 = tid >> 6, ml2 = tid & 63;
    float re = 0.f, im = 0.f;
    #pragma unroll
    for (int ic = 0; ic < 4; ++ic) {
        re += ps[ic][b2][ml2][0];
        im += ps[ic][b2][ml2][1];
    }
    const int oidx = ((g * NB + b2) * NC + oc) * 256 + mq * 64 + ml2;
    zmix[oidx * 2 + 0] = re;
    zmix[oidx * 2 + 1] = im;
}

// ---------------------------------------------------------------------------
// Inverse transform + bypass + GELU (+ projection if FINAL) + next layer's
// row-DFT Y if PRODY.  Body = round-5/6 verified form.
//
// Round-7: srcv/dstv may ALIAS (in-place activation update; __restrict__
// removed on both). Safety: block (h,gb) reads/writes only row h of gb's
// slice; within a block each wave touches only its own 64-col slice, and
// every same-address read precedes the write in program order (depth-1
// prefetch of slice s+1 issues before slice-s stores, disjoint columns).
// ---------------------------------------------------------------------------
template<bool LIFT, bool FINAL, bool PRODY>
__global__ __launch_bounds__(256) void inv_kernel(
    const float* __restrict__ zmix,
    const void* srcv,                   // LIFT ? float x : u32 xb (may == dstv)
    const float* __restrict__ byp_w,
    const float* __restrict__ byp_b,
    const float* __restrict__ lift_w,
    const float* __restrict__ lift_b,
    const float* __restrict__ proj_w,
    const float* __restrict__ proj_b,
    const u16* __restrict__ cwhi,
    const u16* __restrict__ cwlo,
    const u16* __restrict__ ebhi,
    const u16* __restrict__ eblo,
    u32* __restrict__ ypk,              // [gb][h][1024] (PRODY)
    void* dstv,                         // FINAL ? float out : u32 xb (may == srcv)
    int o0, int n)
{
    __shared__ float2 tw[256];
    __shared__ u16 Thi[NC * 40], Tlo[NC * 40];
    __shared__ u16 Whi[NC * 40], Wlo[NC * 40];
    __shared__ float bbl[NC];
    __shared__ float bweffs[NC * 3];
    __shared__ u16 Ghi[PRODY ? 32 * 264 : 1];
    __shared__ u16 Glo[PRODY ? 32 * 264 : 1];
    __shared__ u32 Ypks[PRODY ? 1024 : 1];

    const int tid = threadIdx.x;
    const int h = blockIdx.x;
    const int gb = blockIdx.y;
    const int g = gb >> 2, b = gb & 3;
    const int o = o0 + g;

    {
        float s, cs;
        sincospif((float)tid * (2.0f / 256.0f), &s, &cs);
        tw[tid] = make_float2(cs, s);
    }

    const float* bwp = byp_w + (size_t)(o * 4 + n) * NC * NC;
    const float* bbp = byp_b + (o * 4 + n) * NC;

    if (LIFT) {
        if (tid < 96) {
            const int oc = tid / 3, j = tid % 3;
            float s = 0.f;
            for (int ic = 0; ic < NC; ++ic) s += bwp[oc * NC + ic] * lift_w[ic * 3 + j];
            bweffs[oc * 3 + j] = s;
        } else if (tid < 128) {
            const int oc = tid - 96;
            float s = bbp[oc];
            for (int ic = 0; ic < NC; ++ic) s += bwp[oc * NC + ic] * lift_b[ic];
            bbl[oc] = s;
        }
    } else {
        if (tid < NC) bbl[tid] = bbp[tid];
    }
    __syncthreads();

    for (int idx = tid; idx < NC * NC; idx += 256) {
        const int c = idx >> 5, ic = idx & 31;
        float v;
        if (LIFT) v = (ic < 3) ? bweffs[c * 3 + ic] : 0.f;
        else      v = bwp[idx];
        const u16 hi = f2bf(v);
        Whi[c * 40 + ic] = hi;
        Wlo[c * 40 + ic] = f2bf(v - bf2f(hi));
    }

    // phase A: T[c][l] from zmix; bias folded into T[c][0]
    #pragma unroll
    for (int rep = 0; rep < 2; ++rep) {
        const int it = rep * 256 + tid;
        const int c = it >> 4, l = it & 15;
        const float sl = (l == 0 ? 1.0f : 2.0f) / 256.0f;
        const float* zp = zmix + ((size_t)(gb * NC + c) * 256 + l) * 2;
        float tr = 0.f, ti = 0.f;
        int m = 0;
        #pragma unroll
        for (int k = 0; k < NM; ++k) {
            const float2 z = *(const float2*)(zp + k * 32);
            const float2 t = tw[m];
            tr += z.x * t.x - z.y * t.y;
            ti += z.x * t.y + z.y * t.x;
            m = (m + h) & 255;
        }
        tr *= sl; ti *= sl;
        if (l == 0) tr += bbl[c];
        const u16 rh = f2bf(tr);
        Thi[c * 40 + l] = rh;
        Tlo[c * 40 + l] = f2bf(tr - bf2f(rh));
        const float nti_ = -ti;
        const u16 ih = f2bf(nti_);
        Thi[c * 40 + 16 + l] = ih;
        Tlo[c * 40 + 16 + l] = f2bf(nti_ - bf2f(ih));
    }
    __syncthreads();

    const int lane = tid & 63, wv = tid >> 6;
    const int mrow = lane & 15, q = lane >> 4;

    bf16x8 aThi[2], aTlo[2], aWhi[2], aWlo[2];
    #pragma unroll
    for (int mt = 0; mt < 2; ++mt) {
        const int ro = (mt * 16 + mrow) * 40 + 8 * q;
        aThi[mt] = *(const bf16x8*)&Thi[ro];
        aTlo[mt] = *(const bf16x8*)&Tlo[ro];
        aWhi[mt] = *(const bf16x8*)&Whi[ro];
        aWlo[mt] = *(const bf16x8*)&Wlo[ro];
    }

    float pwv[8];
    float pb = 0.f;
    if (FINAL) {
        #pragma unroll
        for (int mt = 0; mt < 2; ++mt)
            #pragma unroll
            for (int i = 0; i < 4; ++i)
                pwv[mt * 4 + i] = proj_w[mt * 16 + q * 4 + i];
        pb = proj_b[0];
    }

    const float* xbf = LIFT ? (const float*)srcv + (size_t)b * 3 * NPIX + h * NW : nullptr;
    const u32*   xbp = LIFT ? nullptr : (const u32*)srcv + (size_t)gb * NC * NPIX + h * NW;
    u32*   dstp = (u32*)dstv;
    float* dstf = (float*)dstv;

    // depth-1 prefetch of the bypass row (non-LIFT path only)
    u32 cur[8];
    if (!LIFT) {
        const int ncol0 = (wv * 4 + 0) * 16 + mrow;
        #pragma unroll
        for (int j = 0; j < 8; ++j)
            cur[j] = xbp[(size_t)(8 * q + j) * NPIX + ncol0];
    }

    #pragma unroll
    for (int nti = 0; nti < 4; ++nti) {
        const int nt = wv * 4 + nti;
        const int ncol = nt * 16 + mrow;

        const bf16x8 cwh = *(const bf16x8*)(cwhi + ncol * 32 + 8 * q);
        const bf16x8 cwl = *(const bf16x8*)(cwlo + ncol * 32 + 8 * q);

        u32 nxt[8];
        if (!LIFT && nti < 3) {
            const int ncoln = (nt + 1) * 16 + mrow;
            #pragma unroll
            for (int j = 0; j < 8; ++j)
                nxt[j] = xbp[(size_t)(8 * q + j) * NPIX + ncoln];
        }

        bf16x8 xh, xl;
        #pragma unroll
        for (int j = 0; j < 8; ++j) {
            if (LIFT) {
                const int k = 8 * q + j;
                const float v = (k < 3) ? xbf[(size_t)k * NPIX + ncol] : 0.f;
                const u16 hi = f2bf(v);
                xh[j] = (short)hi;
                xl[j] = (short)f2bf(v - bf2f(hi));
            } else {
                xh[j] = (short)(cur[j] & 0xFFFFu);
                xl[j] = (short)(cur[j] >> 16);
            }
        }

        float fpart = 0.f;
        #pragma unroll
        for (int mt = 0; mt < 2; ++mt) {
            f32x4 accT = {0.f, 0.f, 0.f, 0.f};
            f32x4 accW = {0.f, 0.f, 0.f, 0.f};
            accT = MFMA16(aThi[mt], cwh, accT);
            accT = MFMA16(aThi[mt], cwl, accT);
            accT = MFMA16(aTlo[mt], cwh, accT);
            accW = MFMA16(aWhi[mt], xh, accW);
            accW = MFMA16(aWhi[mt], xl, accW);
            accW = MFMA16(aWlo[mt], xh, accW);
            const f32x4 acc = accT + accW;
            if (FINAL) {
                #pragma unroll
                for (int i = 0; i < 4; ++i)
                    fpart += gelu_fast(acc[i]) * pwv[mt * 4 + i];
            } else {
                #pragma unroll
                for (int i = 0; i < 4; ++i) {
                    const int c = mt * 16 + q * 4 + i;
                    const float gl = gelu_fast(acc[i]);
                    dstp[((size_t)gb * NC + c) * NPIX + h * NW + ncol] = packsplit(gl);
                    if (PRODY) {
                        const u16 hi = f2bf(gl);
                        Ghi[c * 264 + ncol] = hi;
                        Glo[c * 264 + ncol] = f2bf(gl - bf2f(hi));
                    }
                }
            }
        }
        if (FINAL) {
            fpart += __shfl_xor(fpart, 16);
            fpart += __shfl_xor(fpart, 32);
            if (q == 0) {
                dstf[(((size_t)b * 4 + o) * NH + h) * NW + nt * 16 + mrow] = fpart + pb;
            }
        }

        if (!LIFT && nti < 3) {
            #pragma unroll
            for (int j = 0; j < 8; ++j) cur[j] = nxt[j];
        }
    }

    // ---- appended (PRODY): next layer's row-DFT for this (h, gb) ----
    if (PRODY) {
        __syncthreads();
        const int mt1 = wv >> 1, nt1 = wv & 1;   // 4 waves = 2x2 tiles
        f32x4 yA = {}, yB = {}, yC = {};
        #pragma unroll
        for (int ks = 0; ks < 8; ++ks) {
            const int ao = (mt1 * 16 + mrow) * 264 + ks * 32 + q * 8;
            const bf16x8 gh = *(const bf16x8*)&Ghi[ao];
            const bf16x8 gl = *(const bf16x8*)&Glo[ao];
            const int bo = (nt1 * 16 + mrow) * 256 + ks * 32 + q * 8;
            const bf16x8 bh = *(const bf16x8*)(ebhi + bo);
            const bf16x8 bl = *(const bf16x8*)(eblo + bo);
            yA = MFMA16(gh, bh, yA);
            yB = MFMA16(gh, bl, yB);
            yC = MFMA16(gl, bh, yC);
        }
        const f32x4 yacc = yA + yB + yC;
        #pragma unroll
        for (int r = 0; r < 4; ++r) {
            const int c = mt1 * 16 + q * 4 + r;
            const int combo = nt1 * 16 + mrow;
            Ypks[c * 32 + combo] = packsplit(yacc[r]);
        }
        __syncthreads();
        u32* yout = ypk + ((size_t)gb * 256 + h) * 1024;
        #pragma unroll
        for (int i = 0; i < 4; ++i)
            yout[i * 256 + tid] = Ypks[i * 256 + tid];
    }
}

// ---------------------------------------------------------------------------
extern "C" void kernel_launch(void* const* d_in, const int* in_sizes, int n_in,
                              void* d_out, int out_size, void* d_ws, size_t ws_size,
                              hipStream_t stream)
{
    const float* x      = (const float*)d_in[0];
    const float* lift_w = (const float*)d_in[1];
    const float* lift_b = (const float*)d_in[2];
    const float* wr     = (const float*)d_in[3];
    const float* wi     = (const float*)d_in[4];
    const float* byp_w  = (const float*)d_in[5];
    const float* byp_b  = (const float*)d_in[6];
    const float* proj_w = (const float*)d_in[7];
    const float* proj_b = (const float*)d_in[8];
    float* ws  = (float*)d_ws;

    // Single in-place activation buffer (block (h,gb) of layer n+1 reads
    // exactly what block (h,gb) of layer n wrote; per-wave col slices are
    // disjoint and read-before-write holds in program order).
    // G=4 footprint ~159MB vs 292MB double-buffered -> likely engages.
    auto need_bytes = [](int Gq) -> size_t {
        size_t bts = 0;
        bts += (size_t)4 * 8192 * sizeof(u16);          // cw/eb tables
        bts += (size_t)65536 * 4;                       // zlift
        bts += (size_t)4 * 256 * 1024 * 4;              // ylift
        bts += (size_t)Gq * NB * 256 * 1024 * 4;        // y
        bts += (size_t)Gq * ZG * 4 * 2;                 // zred + zmix
        bts += (size_t)Gq * NP * 4;                     // buf (single)
        return bts;
    };
    const int G = (ws_size >= need_bytes(4)) ? 4 : 2;

    u16* cwhi = (u16*)ws;
    u16* cwlo = cwhi + 8192;
    u16* ebhi = cwlo + 8192;
    u16* eblo = ebhi + 8192;
    float* zlift = ws + 16384;
    u32* ylift = (u32*)(zlift + 65536);                      // 4*256*1024
    u32* y     = ylift + (size_t)4 * 256 * 1024;             // G*4*256*1024
    float* zred = (float*)(y + (size_t)G * NB * 256 * 1024);
    float* zmix = zred + (size_t)G * ZG;
    u32* buf  = (u32*)(zmix + (size_t)G * ZG);

    tab_prep<<<64, 256, 0, stream>>>(cwhi, cwlo, ebhi, eblo);

    // lift spectrum is o-independent: stage-1 + stage-2 once
    s1_lift<<<dim3(NC, NB, 4), 256, 0, stream>>>(x, lift_w, lift_b, ebhi, eblo, ylift);
    s2_kernel<<<dim3(NC, NB), 256, 0, stream>>>(ylift, ebhi, eblo, zlift);

    for (int o0 = 0; o0 < 4; o0 += G) {
        for (int n = 0; n < 4; ++n) {
            const bool lift = (n == 0);
            const bool fin  = (n == 3);

            if (!lift)
                s2_kernel<<<dim3(NC, G * NB), 256, 0, stream>>>(y, ebhi, eblo, zred);

            mix_kernel<<<dim3(NC, 4, G), 256, 0, stream>>>(
                lift ? zlift : zred, zmix, wr, wi, o0, n, lift ? 0 : 1);

            dim3 igrid(NH, G * NB);
            if (fin) {
                inv_kernel<false, true, false><<<igrid, 256, 0, stream>>>(
                    zmix, buf, byp_w, byp_b, lift_w, lift_b, proj_w, proj_b,
                    cwhi, cwlo, ebhi, eblo, y, d_out, o0, n);
            } else if (lift) {
                inv_kernel<true, false, true><<<igrid, 256, 0, stream>>>(
                    zmix, x, byp_w, byp_b, lift_w, lift_b, proj_w, proj_b,
                    cwhi, cwlo, ebhi, eblo, y, buf, o0, n);
            } else {
                inv_kernel<false, false, true><<<igrid, 256, 0, stream>>>(
                    zmix, buf, byp_w, byp_b, lift_w, lift_b, proj_w, proj_b,
                    cwhi, cwlo, ebhi, eblo, y, buf, o0, n);
            }
        }
    }
}